// Round 5
// baseline (354.826 us; speedup 1.0000x reference)
//
#include <hip/hip_runtime.h>
#include <hip/hip_bf16.h>

typedef __attribute__((ext_vector_type(8))) short bf16x8;
typedef __attribute__((ext_vector_type(4))) short bf16x4;
typedef __attribute__((ext_vector_type(4))) float f32x4;
typedef __attribute__((ext_vector_type(4))) int   i32x4;
typedef __attribute__((ext_vector_type(2))) unsigned u32x2;

#define D_MODEL 2048
#define NTOK    4096   // B*S
#define NH      16
#define HD      128
#define SEQ     2048

__device__ __forceinline__ short f2bf(float f) {
  unsigned u = __builtin_bit_cast(unsigned, f);
  unsigned r = u + 0x7FFFu + ((u >> 16) & 1u);   // RNE
  return (short)(r >> 16);
}
__device__ __forceinline__ float bf2f(short s) {
  return __builtin_bit_cast(float, ((unsigned)(unsigned short)s) << 16);
}

__device__ __forceinline__ float exp2fast(float x) {
#if __has_builtin(__builtin_amdgcn_exp2f)
  return __builtin_amdgcn_exp2f(x);
#else
  return exp2f(x);
#endif
}

// pack 2 fp32 -> 2 bf16 (RNE) in one instr
__device__ __forceinline__ unsigned cvt_pk_bf16(float a, float b) {
  unsigned r;
  asm("v_cvt_pk_bf16_f32 %0, %1, %2" : "=v"(r) : "v"(a), "v"(b));
  return r;
}

#if __has_builtin(__builtin_amdgcn_mfma_f32_16x16x16bf16_1k)
#define MFMA16_ASM 0
__device__ __forceinline__ f32x4 mfma16(bf16x4 a, bf16x4 b, f32x4 c) {
  return __builtin_amdgcn_mfma_f32_16x16x16bf16_1k(a, b, c, 0, 0, 0);
}
#else
#define MFMA16_ASM 1
__device__ __forceinline__ f32x4 mfma16(bf16x4 a, bf16x4 b, f32x4 c) {
  asm("s_nop 3\n\tv_mfma_f32_16x16x16_bf16 %0, %1, %2, %0" : "+v"(c) : "v"(a), "v"(b));
  return c;
}
#endif

// async global->LDS, 16B per lane. LDS dst must be wave-uniform; HW writes lane i at dst + i*16.
__device__ __forceinline__ void gload_lds16(const void* g, void* l) {
  typedef __attribute__((address_space(1))) const unsigned gu32;
  typedef __attribute__((address_space(3))) unsigned lu32;
  __builtin_amdgcn_global_load_lds((gu32*)(uintptr_t)g,
                                   (lu32*)(unsigned)(uintptr_t)l, 16, 0, 0);
}

// ---------------- 1. fp32 -> bf16 cast (vectorized) ----------------
__global__ __launch_bounds__(256) void cast_bf16(const float* __restrict__ in,
                                                 short* __restrict__ out, int n4) {
  int i = blockIdx.x * 256 + threadIdx.x;
  if (i >= n4) return;
  float4 v = ((const float4*)in)[i];
  short4 o;
  o.x = f2bf(v.x); o.y = f2bf(v.y); o.z = f2bf(v.z); o.w = f2bf(v.w);
  ((short4*)out)[i] = o;
}

// ---------------- 2. W (KxN) -> W^T (NxK) bf16, LDS-tiled ----------------
__global__ __launch_bounds__(256) void wtrans(const float* __restrict__ w0,
                                              const float* __restrict__ w1,
                                              const float* __restrict__ w2,
                                              const float* __restrict__ w3,
                                              short* __restrict__ wt) {
  int z = blockIdx.z;
  const float* W = (z == 0) ? w0 : (z == 1) ? w1 : (z == 2) ? w2 : w3;
  short* O = wt + (size_t)z * D_MODEL * D_MODEL;
  int n0 = blockIdx.x * 64, k0 = blockIdx.y * 64;
  __shared__ short T[64 * 136];
  int tid = threadIdx.x;
#pragma unroll
  for (int it = 0; it < 4; ++it) {
    int f = it * 256 + tid, kk = f >> 4, nc = f & 15;
    float4 v = *(const float4*)&W[(size_t)(k0 + kk) * D_MODEL + n0 + nc * 4];
    short4 o;
    o.x = f2bf(v.x); o.y = f2bf(v.y); o.z = f2bf(v.z); o.w = f2bf(v.w);
    *(short4*)&T[kk * 136 + nc * 4] = o;
  }
  __syncthreads();
#pragma unroll
  for (int it = 0; it < 4; ++it) {
    int u = it * 256 + tid, nn = u >> 4, kc = u & 15;
    short4 o;
    o.x = T[(kc * 4 + 0) * 136 + nn];
    o.y = T[(kc * 4 + 1) * 136 + nn];
    o.z = T[(kc * 4 + 2) * 136 + nn];
    o.w = T[(kc * 4 + 3) * 136 + nn];
    *(short4*)&O[(size_t)(n0 + nn) * D_MODEL + k0 + kc * 4] = o;
  }
}

// ---------------- 3/7. GEMM  C[M,N] = A[M,K] * Bt[N,K]^T  (m97 structure) ----------------
template <bool OUTBF16>
__global__ __launch_bounds__(256) void gemm_bt(const short* __restrict__ A,
                                               const short* __restrict__ Bt,
                                               void* __restrict__ Cv,
                                               int M, int N, int K) {
  __shared__ short As[128 * 32];
  __shared__ short Bs[128 * 32];
  int tid = threadIdx.x;
  int w = tid >> 6, lane = tid & 63, c = lane & 15, g = lane >> 4;
  int z = blockIdx.z;
  const short* Bb = Bt + (size_t)z * K * N;
  int m0 = blockIdx.y * 128, n0 = blockIdx.x * 128;
  int wm = w >> 1, wn = w & 1;
  f32x4 acc[4][4] = {};
  int lrow = lane >> 2, lk = (lane & 3) * 8;

  for (int kk = 0; kk < K; kk += 32) {
    __syncthreads();
#pragma unroll
    for (int q = 0; q < 2; ++q) {
      int ch = 2 * w + q;  // wave-uniform chunk id (16 rows of 32 bf16 = 1KB)
      gload_lds16(A  + (size_t)(m0 + ch * 16 + lrow) * K + kk + lk, &As[ch * 512]);
      gload_lds16(Bb + (size_t)(n0 + ch * 16 + lrow) * K + kk + lk, &Bs[ch * 512]);
    }
    __syncthreads();
    bf16x8 af[4], bfr[4];
#pragma unroll
    for (int mi = 0; mi < 4; ++mi)
      af[mi] = *(const bf16x8*)&As[(wm * 64 + mi * 16 + c) * 32 + g * 8];
#pragma unroll
    for (int ni = 0; ni < 4; ++ni)
      bfr[ni] = *(const bf16x8*)&Bs[(wn * 64 + ni * 16 + c) * 32 + g * 8];
#pragma unroll
    for (int mi = 0; mi < 4; ++mi)
#pragma unroll
      for (int ni = 0; ni < 4; ++ni)
        acc[mi][ni] = __builtin_amdgcn_mfma_f32_16x16x32_bf16(af[mi], bfr[ni],
                                                              acc[mi][ni], 0, 0, 0);
  }
  int row0 = m0 + wm * 64, col0 = n0 + wn * 64;
  if (OUTBF16) {
    short* Cb = (short*)Cv + (size_t)z * M * N;
#pragma unroll
    for (int mi = 0; mi < 4; ++mi)
#pragma unroll
      for (int ni = 0; ni < 4; ++ni)
#pragma unroll
        for (int i = 0; i < 4; ++i)
          Cb[(size_t)(row0 + mi * 16 + g * 4 + i) * N + col0 + ni * 16 + c] =
              f2bf(acc[mi][ni][i]);
  } else {
    float* Cf = (float*)Cv;
#pragma unroll
    for (int mi = 0; mi < 4; ++mi)
#pragma unroll
      for (int ni = 0; ni < 4; ++ni)
#pragma unroll
        for (int i = 0; i < 4; ++i)
          Cf[(size_t)(row0 + mi * 16 + g * 4 + i) * N + col0 + ni * 16 + c] =
              acc[mi][ni][i];
  }
}

// ---------------- 4. fused RMSNorm + RoPE (q,k), one wave per (token,head) ----------------
// Q is pre-scaled by 1/sqrt(128)*log2(e) so flash's QK^T lands directly in the
// log2 domain (softmax uses raw v_exp 2^x) with the 1/sqrt(d) scale folded in.
__global__ __launch_bounds__(256) void norm_rope(const short* __restrict__ qkv16,
                                                 const float* __restrict__ cosb,
                                                 const float* __restrict__ sinb,
                                                 const float* __restrict__ gq,
                                                 const float* __restrict__ gk,
                                                 short* __restrict__ qn,
                                                 short* __restrict__ kn) {
  int z = blockIdx.y;  // 0=q, 1=k
  const short* X = qkv16 + (size_t)z * NTOK * D_MODEL;
  const float* gg = z ? gk : gq;
  short* O = z ? kn : qn;
  int w = threadIdx.x >> 6, lane = threadIdx.x & 63;
  int p = blockIdx.x * 4 + w;          // (token,head) pair
  int token = p >> 4, h = p & 15;
  int v = *(const int*)&X[(size_t)token * D_MODEL + h * HD + lane * 2];
  float x0 = bf2f((short)(v & 0xffff));
  float x1 = bf2f((short)((unsigned)v >> 16));
  float ss = x0 * x0 + x1 * x1;
#pragma unroll
  for (int mk = 32; mk; mk >>= 1) ss += __shfl_xor(ss, mk);
  float rs = rsqrtf(ss * (1.f / 128.f) + 1e-5f);
  float qs = z ? 1.0f : 0.12751744f;   // 1/sqrt(128) * log2(e) for Q only
  rs *= qs;
  float xr = x0 * rs * gg[lane * 2];
  float xi = x1 * rs * gg[lane * 2 + 1];
  float cc = cosb[(size_t)token * 64 + lane];
  float sn = sinb[(size_t)token * 64 + lane];
  float or_ = xr * cc - xi * sn;
  float oi_ = xr * sn + xi * cc;
  int b = token >> 11, sidx = token & 2047;
  size_t dst = ((size_t)(b * NH + h) * SEQ + sidx) * HD + lane * 2;
  unsigned pk = (unsigned)(unsigned short)f2bf(or_) |
                ((unsigned)(unsigned short)f2bf(oi_) << 16);
  *(unsigned*)&O[dst] = pk;
}

// ---------------- 5. V (token-major bf16) -> V^T (B,H,128,S) ----------------
__global__ __launch_bounds__(256) void vtrans(const short* __restrict__ v16,
                                              short* __restrict__ vt) {
  int st = blockIdx.x, bh = blockIdx.y;
  int b = bh >> 4, h = bh & 15;
  int t0 = b * SEQ + st * 64;
  __shared__ short Lt[64 * 136];
  int tid = threadIdx.x;
#pragma unroll
  for (int it = 0; it < 4; ++it) {
    int f = it * 256 + tid, tk = f >> 4, ch = f & 15;
    *(i32x4*)&Lt[tk * 136 + ch * 8] =
        *(const i32x4*)&v16[(size_t)(t0 + tk) * D_MODEL + h * HD + ch * 8];
  }
  __syncthreads();
#pragma unroll
  for (int it = 0; it < 4; ++it) {
    int u = it * 256 + tid, d = u >> 3, kg = u & 7;
    bf16x8 o;
#pragma unroll
    for (int j = 0; j < 8; ++j) o[j] = Lt[(kg * 8 + j) * 136 + d];
    *(bf16x8*)&vt[(size_t)(bh * HD + d) * SEQ + st * 64 + kg * 8] = o;
  }
}

// ---------------- 6. flash attention: swapped QK^T, in-register P, scalar softmax state ----------------
// 8 waves x 16 q-rows = 128 q/block. K tile [64 key][256B], V tile [128 d][128B],
// both XOR-swizzled (phys = row*RB + (col ^ ((row&7)<<4))), staged by global_load_lds
// with pre-swizzled source, double-buffered, 1 barrier/iter.
// QK^T: mfma32(K, Q) -> lane holds S[k = kt*16 + g*4 + i][q = c]  (log2-domain, Q pre-scaled)
// PV:   mfma16(Vt, P) with P packed in-register -> acc[d = db*16 + g*4 + i][q = c]
__global__ __launch_bounds__(512, 4) void flash(const short* __restrict__ qn,
                                                const short* __restrict__ kn,
                                                const short* __restrict__ vt,
                                                short* __restrict__ attn) {
  __shared__ short Ks[2][64 * 128];   // 2 x 16KB
  __shared__ short Vs[2][128 * 64];   // 2 x 16KB
  int tid = threadIdx.x, w = tid >> 6, lane = tid & 63, c = lane & 15, g = lane >> 4;
  int bh = blockIdx.y;
  int q0 = blockIdx.x * 128 + w * 16;
  const size_t base = (size_t)bh * SEQ * HD;
  const short* Kg = kn + base;
  const short* Vg = vt + base;

  bf16x8 qf[4];
#pragma unroll
  for (int kf = 0; kf < 4; ++kf)
    qf[kf] = *(const bf16x8*)&qn[base + (size_t)(q0 + c) * HD + kf * 32 + g * 8];

  f32x4 acc[8] = {};
  float m_ = -1e30f, l_ = 0.f;

  // staging: 16 K-chunks + 16 V-chunks of 1KB; wave w stages chunks {2w, 2w+1}
  int ksrc[2], vsrc[2];
#pragma unroll
  for (int p = 0; p < 2; ++p) {
    int ch = w * 2 + p;
    int o = ch * 1024 + lane * 16;                   // linear LDS byte offset
    int kr = o >> 8, kc = o & 255;                   // K: 256B rows
    ksrc[p] = kr * HD + ((kc ^ ((kr & 7) << 4)) >> 1);
    int vr = o >> 7, vc = o & 127;                   // V: 128B rows
    vsrc[p] = vr * SEQ + ((vc ^ ((vr & 7) << 4)) >> 1);
  }
  // read offsets (bytes), loop-invariant
  int swz = (c & 7) << 4;
  int koff[4], voff[4];
#pragma unroll
  for (int kf = 0; kf < 4; ++kf) koff[kf] = c * 256 + ((kf * 64 + g * 16) ^ swz);
#pragma unroll
  for (int kt = 0; kt < 4; ++kt) voff[kt] = c * 128 + ((kt * 32 + g * 8) ^ swz);

  // prologue: stage tile 0 into buffer 0
#pragma unroll
  for (int p = 0; p < 2; ++p) {
    int ch = w * 2 + p;
    gload_lds16(Kg + ksrc[p], (char*)&Ks[0][0] + ch * 1024);
    gload_lds16(Vg + vsrc[p], (char*)&Vs[0][0] + ch * 1024);
  }

  const int NT = SEQ / 64;
  for (int t = 0; t < NT; ++t) {
    int cur = t & 1;
    __syncthreads();           // vmcnt(0) drain => buf[cur] ready; buf[cur^1] free
    if (t + 1 < NT) {
      int k0n = (t + 1) * 64;
#pragma unroll
      for (int p = 0; p < 2; ++p) {
        int ch = w * 2 + p;
        gload_lds16(Kg + (size_t)k0n * HD + ksrc[p], (char*)&Ks[cur ^ 1][0] + ch * 1024);
        gload_lds16(Vg + k0n + vsrc[p],              (char*)&Vs[cur ^ 1][0] + ch * 1024);
      }
    }
    const char* Kb = (const char*)&Ks[cur][0];
    const char* Vb = (const char*)&Vs[cur][0];

    // QK^T (swapped): s[kt] lane(c,g)[i] = S[kt*16 + g*4 + i][q0 + c], log2 domain
    f32x4 s[4];
    __builtin_amdgcn_s_setprio(1);
#pragma unroll
    for (int kt = 0; kt < 4; ++kt) {
      f32x4 sa = {0.f, 0.f, 0.f, 0.f};
#pragma unroll
      for (int kf = 0; kf < 4; ++kf) {
        bf16x8 kb = *(const bf16x8*)(Kb + kt * 4096 + koff[kf]);
        sa = __builtin_amdgcn_mfma_f32_16x16x32_bf16(kb, qf[kf], sa, 0, 0, 0);
      }
      s[kt] = sa;
    }
    __builtin_amdgcn_s_setprio(0);

    // per-lane scalar online softmax (q = c)
    float pmax = -1e30f;
#pragma unroll
    for (int kt = 0; kt < 4; ++kt)
#pragma unroll
      for (int i = 0; i < 4; ++i) pmax = fmaxf(pmax, s[kt][i]);
    pmax = fmaxf(pmax, __shfl_xor(pmax, 16));
    pmax = fmaxf(pmax, __shfl_xor(pmax, 32));
    if (!__all(pmax <= m_ + 11.5f)) {   // defer-max: p bounded by 2^11.5
      float mn = fmaxf(m_, pmax);
      float al = exp2fast(m_ - mn);
      m_ = mn; l_ *= al;
#pragma unroll
      for (int db = 0; db < 8; ++db)
#pragma unroll
        for (int i = 0; i < 4; ++i) acc[db][i] *= al;
    }
    float r = 0.f;
#pragma unroll
    for (int kt = 0; kt < 4; ++kt)
#pragma unroll
      for (int i = 0; i < 4; ++i) {
        float p = exp2fast(s[kt][i] - m_);
        r += p; s[kt][i] = p;
      }
    r += __shfl_xor(r, 16);
    r += __shfl_xor(r, 32);
    l_ += r;

    // pack P to bf16 in-register: pb[kt] = B-fragment of mfma16 (P[k][q=c])
    bf16x4 pb[4];
#pragma unroll
    for (int kt = 0; kt < 4; ++kt) {
      u32x2 tpk;
      tpk[0] = cvt_pk_bf16(s[kt][0], s[kt][1]);
      tpk[1] = cvt_pk_bf16(s[kt][2], s[kt][3]);
      pb[kt] = __builtin_bit_cast(bf16x4, tpk);
    }

    // PV: acc[db] += Vt-frag x pb  (16x16x16)
    __builtin_amdgcn_s_setprio(1);
#pragma unroll
    for (int kt = 0; kt < 4; ++kt)
#pragma unroll
      for (int db = 0; db < 8; ++db) {
        bf16x4 va = *(const bf16x4*)(Vb + db * 2048 + voff[kt]);
        acc[db] = mfma16(va, pb[kt], acc[db]);
      }
    __builtin_amdgcn_s_setprio(0);
  }
#if MFMA16_ASM
  asm volatile("s_nop 7\n\ts_nop 7");
#endif

  int b = bh >> 4, h = bh & 15;
  float linv = 1.f / l_;
#pragma unroll
  for (int db = 0; db < 8; ++db) {
    short4 o;
    o.x = f2bf(acc[db][0] * linv);
    o.y = f2bf(acc[db][1] * linv);
    o.z = f2bf(acc[db][2] * linv);
    o.w = f2bf(acc[db][3] * linv);
    *(short4*)&attn[(size_t)(b * SEQ + q0 + c) * D_MODEL + h * HD + db * 16 + g * 4] = o;
  }
}

// ---------------- launch ----------------
extern "C" void kernel_launch(void* const* d_in, const int* in_sizes, int n_in,
                              void* d_out, int out_size, void* d_ws, size_t ws_size,
                              hipStream_t stream) {
  const float* hs   = (const float*)d_in[0];
  const float* fcos = (const float*)d_in[1];
  const float* fsin = (const float*)d_in[2];
  const float* Wq   = (const float*)d_in[3];
  const float* Wk   = (const float*)d_in[4];
  const float* Wv   = (const float*)d_in[5];
  const float* Wo   = (const float*)d_in[6];
  const float* gq   = (const float*)d_in[7];
  const float* gk   = (const float*)d_in[8];

  char* ws = (char*)d_ws;
  short* hs16  = (short*)ws;                        // 16,777,216 B
  short* Wt    = (short*)(ws + 16777216);           // 33,554,432 B (4 matrices, N-major)
  short* qkv16 = (short*)(ws + 50331648);           // 50,331,648 B (q,k,v bf16 token-major)
  short* qn    = (short*)(ws + 100663296);          // 16,777,216 B (B,H,S,128)
  short* kn    = (short*)(ws + 117440512);          // 16,777,216 B
  short* vt    = (short*)(ws + 134217728);          // 16,777,216 B (B,H,128,S)
  short* attn16 = qkv16;  // reuse q slot (dead after norm_rope)

  cast_bf16<<<8192, 256, 0, stream>>>(hs, hs16, NTOK * D_MODEL / 4);
  wtrans<<<dim3(32, 32, 4), 256, 0, stream>>>(Wq, Wk, Wv, Wo, Wt);
  gemm_bt<true><<<dim3(16, 32, 3), 256, 0, stream>>>(hs16, Wt, qkv16,
                                                     NTOK, D_MODEL, D_MODEL);
  norm_rope<<<dim3(16384, 2), 256, 0, stream>>>(qkv16, fcos, fsin, gq, gk, qn, kn);
  vtrans<<<dim3(32, 32), 256, 0, stream>>>(qkv16 + (size_t)2 * NTOK * D_MODEL, vt);
  flash<<<dim3(16, 32), 512, 0, stream>>>(qn, kn, vt, attn16);
  gemm_bt<false><<<dim3(16, 32, 1), 256, 0, stream>>>(attn16,
                                                      Wt + (size_t)3 * D_MODEL * D_MODEL,
                                                      d_out, NTOK, D_MODEL, D_MODEL);
}

// Round 6
// 354.663 us; speedup vs baseline: 1.0005x; 1.0005x over previous
//
#include <hip/hip_runtime.h>
#include <hip/hip_bf16.h>

typedef __attribute__((ext_vector_type(8))) short bf16x8;
typedef __attribute__((ext_vector_type(4))) short bf16x4;
typedef __attribute__((ext_vector_type(4))) float f32x4;
typedef __attribute__((ext_vector_type(4))) int   i32x4;
typedef __attribute__((ext_vector_type(2))) unsigned u32x2;

#define D_MODEL 2048
#define NTOK    4096   // B*S
#define NH      16
#define HD      128
#define SEQ     2048

__device__ __forceinline__ short f2bf(float f) {
  unsigned u = __builtin_bit_cast(unsigned, f);
  unsigned r = u + 0x7FFFu + ((u >> 16) & 1u);   // RNE
  return (short)(r >> 16);
}
__device__ __forceinline__ float bf2f(short s) {
  return __builtin_bit_cast(float, ((unsigned)(unsigned short)s) << 16);
}

__device__ __forceinline__ float exp2fast(float x) {
#if __has_builtin(__builtin_amdgcn_exp2f)
  return __builtin_amdgcn_exp2f(x);
#else
  return exp2f(x);
#endif
}

// pack 2 fp32 -> 2 bf16 (RNE) in one instr
__device__ __forceinline__ unsigned cvt_pk_bf16(float a, float b) {
  unsigned r;
  asm("v_cvt_pk_bf16_f32 %0, %1, %2" : "=v"(r) : "v"(a), "v"(b));
  return r;
}

#if __has_builtin(__builtin_amdgcn_mfma_f32_16x16x16bf16_1k)
#define MFMA16_ASM 0
__device__ __forceinline__ f32x4 mfma16(bf16x4 a, bf16x4 b, f32x4 c) {
  return __builtin_amdgcn_mfma_f32_16x16x16bf16_1k(a, b, c, 0, 0, 0);
}
#else
#define MFMA16_ASM 1
__device__ __forceinline__ f32x4 mfma16(bf16x4 a, bf16x4 b, f32x4 c) {
  asm("s_nop 3\n\tv_mfma_f32_16x16x16_bf16 %0, %1, %2, %0" : "+v"(c) : "v"(a), "v"(b));
  return c;
}
#endif

// async global->LDS, 16B per lane. LDS dst must be wave-uniform; HW writes lane i at dst + i*16.
__device__ __forceinline__ void gload_lds16(const void* g, void* l) {
  typedef __attribute__((address_space(1))) const unsigned gu32;
  typedef __attribute__((address_space(3))) unsigned lu32;
  __builtin_amdgcn_global_load_lds((gu32*)(uintptr_t)g,
                                   (lu32*)(unsigned)(uintptr_t)l, 16, 0, 0);
}

// ---------------- 1. fp32 -> bf16 cast (vectorized) ----------------
__global__ __launch_bounds__(256) void cast_bf16(const float* __restrict__ in,
                                                 short* __restrict__ out, int n4) {
  int i = blockIdx.x * 256 + threadIdx.x;
  if (i >= n4) return;
  float4 v = ((const float4*)in)[i];
  short4 o;
  o.x = f2bf(v.x); o.y = f2bf(v.y); o.z = f2bf(v.z); o.w = f2bf(v.w);
  ((short4*)out)[i] = o;
}

// ---------------- 2. W (KxN) -> W^T (NxK) bf16, LDS-tiled ----------------
__global__ __launch_bounds__(256) void wtrans(const float* __restrict__ w0,
                                              const float* __restrict__ w1,
                                              const float* __restrict__ w2,
                                              const float* __restrict__ w3,
                                              short* __restrict__ wt) {
  int z = blockIdx.z;
  const float* W = (z == 0) ? w0 : (z == 1) ? w1 : (z == 2) ? w2 : w3;
  short* O = wt + (size_t)z * D_MODEL * D_MODEL;
  int n0 = blockIdx.x * 64, k0 = blockIdx.y * 64;
  __shared__ short T[64 * 136];
  int tid = threadIdx.x;
#pragma unroll
  for (int it = 0; it < 4; ++it) {
    int f = it * 256 + tid, kk = f >> 4, nc = f & 15;
    float4 v = *(const float4*)&W[(size_t)(k0 + kk) * D_MODEL + n0 + nc * 4];
    short4 o;
    o.x = f2bf(v.x); o.y = f2bf(v.y); o.z = f2bf(v.z); o.w = f2bf(v.w);
    *(short4*)&T[kk * 136 + nc * 4] = o;
  }
  __syncthreads();
#pragma unroll
  for (int it = 0; it < 4; ++it) {
    int u = it * 256 + tid, nn = u >> 4, kc = u & 15;
    short4 o;
    o.x = T[(kc * 4 + 0) * 136 + nn];
    o.y = T[(kc * 4 + 1) * 136 + nn];
    o.z = T[(kc * 4 + 2) * 136 + nn];
    o.w = T[(kc * 4 + 3) * 136 + nn];
    *(short4*)&O[(size_t)(n0 + nn) * D_MODEL + k0 + kc * 4] = o;
  }
}

// ---------------- 3/7. GEMM  C[M,N] = A[M,K] * Bt[N,K]^T  (m97 structure) ----------------
template <bool OUTBF16>
__global__ __launch_bounds__(256) void gemm_bt(const short* __restrict__ A,
                                               const short* __restrict__ Bt,
                                               void* __restrict__ Cv,
                                               int M, int N, int K) {
  __shared__ short As[128 * 32];
  __shared__ short Bs[128 * 32];
  int tid = threadIdx.x;
  int w = tid >> 6, lane = tid & 63, c = lane & 15, g = lane >> 4;
  int z = blockIdx.z;
  const short* Bb = Bt + (size_t)z * K * N;
  int m0 = blockIdx.y * 128, n0 = blockIdx.x * 128;
  int wm = w >> 1, wn = w & 1;
  f32x4 acc[4][4] = {};
  int lrow = lane >> 2, lk = (lane & 3) * 8;

  for (int kk = 0; kk < K; kk += 32) {
    __syncthreads();
#pragma unroll
    for (int q = 0; q < 2; ++q) {
      int ch = 2 * w + q;  // wave-uniform chunk id (16 rows of 32 bf16 = 1KB)
      gload_lds16(A  + (size_t)(m0 + ch * 16 + lrow) * K + kk + lk, &As[ch * 512]);
      gload_lds16(Bb + (size_t)(n0 + ch * 16 + lrow) * K + kk + lk, &Bs[ch * 512]);
    }
    __syncthreads();
    bf16x8 af[4], bfr[4];
#pragma unroll
    for (int mi = 0; mi < 4; ++mi)
      af[mi] = *(const bf16x8*)&As[(wm * 64 + mi * 16 + c) * 32 + g * 8];
#pragma unroll
    for (int ni = 0; ni < 4; ++ni)
      bfr[ni] = *(const bf16x8*)&Bs[(wn * 64 + ni * 16 + c) * 32 + g * 8];
#pragma unroll
    for (int mi = 0; mi < 4; ++mi)
#pragma unroll
      for (int ni = 0; ni < 4; ++ni)
        acc[mi][ni] = __builtin_amdgcn_mfma_f32_16x16x32_bf16(af[mi], bfr[ni],
                                                              acc[mi][ni], 0, 0, 0);
  }
  int row0 = m0 + wm * 64, col0 = n0 + wn * 64;
  if (OUTBF16) {
    short* Cb = (short*)Cv + (size_t)z * M * N;
#pragma unroll
    for (int mi = 0; mi < 4; ++mi)
#pragma unroll
      for (int ni = 0; ni < 4; ++ni)
#pragma unroll
        for (int i = 0; i < 4; ++i)
          Cb[(size_t)(row0 + mi * 16 + g * 4 + i) * N + col0 + ni * 16 + c] =
              f2bf(acc[mi][ni][i]);
  } else {
    float* Cf = (float*)Cv;
#pragma unroll
    for (int mi = 0; mi < 4; ++mi)
#pragma unroll
      for (int ni = 0; ni < 4; ++ni)
#pragma unroll
        for (int i = 0; i < 4; ++i)
          Cf[(size_t)(row0 + mi * 16 + g * 4 + i) * N + col0 + ni * 16 + c] =
              acc[mi][ni][i];
  }
}

// ---------------- 4. fused RMSNorm + RoPE (q,k), one wave per (token,head) ----------------
// Q is pre-scaled by 1/sqrt(128)*log2(e) so flash's QK^T lands directly in the
// log2 domain (softmax uses raw v_exp 2^x) with the 1/sqrt(d) scale folded in.
__global__ __launch_bounds__(256) void norm_rope(const short* __restrict__ qkv16,
                                                 const float* __restrict__ cosb,
                                                 const float* __restrict__ sinb,
                                                 const float* __restrict__ gq,
                                                 const float* __restrict__ gk,
                                                 short* __restrict__ qn,
                                                 short* __restrict__ kn) {
  int z = blockIdx.y;  // 0=q, 1=k
  const short* X = qkv16 + (size_t)z * NTOK * D_MODEL;
  const float* gg = z ? gk : gq;
  short* O = z ? kn : qn;
  int w = threadIdx.x >> 6, lane = threadIdx.x & 63;
  int p = blockIdx.x * 4 + w;          // (token,head) pair
  int token = p >> 4, h = p & 15;
  int v = *(const int*)&X[(size_t)token * D_MODEL + h * HD + lane * 2];
  float x0 = bf2f((short)(v & 0xffff));
  float x1 = bf2f((short)((unsigned)v >> 16));
  float ss = x0 * x0 + x1 * x1;
#pragma unroll
  for (int mk = 32; mk; mk >>= 1) ss += __shfl_xor(ss, mk);
  float rs = rsqrtf(ss * (1.f / 128.f) + 1e-5f);
  float qs = z ? 1.0f : 0.12751744f;   // 1/sqrt(128) * log2(e) for Q only
  rs *= qs;
  float xr = x0 * rs * gg[lane * 2];
  float xi = x1 * rs * gg[lane * 2 + 1];
  float cc = cosb[(size_t)token * 64 + lane];
  float sn = sinb[(size_t)token * 64 + lane];
  float or_ = xr * cc - xi * sn;
  float oi_ = xr * sn + xi * cc;
  int b = token >> 11, sidx = token & 2047;
  size_t dst = ((size_t)(b * NH + h) * SEQ + sidx) * HD + lane * 2;
  unsigned pk = (unsigned)(unsigned short)f2bf(or_) |
                ((unsigned)(unsigned short)f2bf(oi_) << 16);
  *(unsigned*)&O[dst] = pk;
}

// ---------------- 5. V (token-major bf16) -> V^T (B,H,128,S) ----------------
__global__ __launch_bounds__(256) void vtrans(const short* __restrict__ v16,
                                              short* __restrict__ vt) {
  int st = blockIdx.x, bh = blockIdx.y;
  int b = bh >> 4, h = bh & 15;
  int t0 = b * SEQ + st * 64;
  __shared__ short Lt[64 * 136];
  int tid = threadIdx.x;
#pragma unroll
  for (int it = 0; it < 4; ++it) {
    int f = it * 256 + tid, tk = f >> 4, ch = f & 15;
    *(i32x4*)&Lt[tk * 136 + ch * 8] =
        *(const i32x4*)&v16[(size_t)(t0 + tk) * D_MODEL + h * HD + ch * 8];
  }
  __syncthreads();
#pragma unroll
  for (int it = 0; it < 4; ++it) {
    int u = it * 256 + tid, d = u >> 3, kg = u & 7;
    bf16x8 o;
#pragma unroll
    for (int j = 0; j < 8; ++j) o[j] = Lt[(kg * 8 + j) * 136 + d];
    *(bf16x8*)&vt[(size_t)(bh * HD + d) * SEQ + st * 64 + kg * 8] = o;
  }
}

// ---------------- 6. flash attention: swapped QK^T, in-register P, scalar softmax state ----------------
// 8 waves x 16 q-rows = 128 q/block. K tile [64 key][256B], V tile [128 d][128B],
// both XOR-swizzled (phys = row*RB + (col ^ ((row&7)<<4))), staged by global_load_lds
// with pre-swizzled source, double-buffered, 1 barrier/iter.
// QK^T: mfma32(K, Q) -> lane holds S[k = kt*16 + g*4 + i][q = c]  (log2-domain, Q pre-scaled)
// PV:   mfma16(Vt, P) with P packed in-register -> acc[d = db*16 + g*4 + i][q = c]
__global__ __launch_bounds__(512, 4) void flash(const short* __restrict__ qn,
                                                const short* __restrict__ kn,
                                                const short* __restrict__ vt,
                                                short* __restrict__ attn) {
  __shared__ short Ks[2][64 * 128];   // 2 x 16KB
  __shared__ short Vs[2][128 * 64];   // 2 x 16KB
  int tid = threadIdx.x, w = tid >> 6, lane = tid & 63, c = lane & 15, g = lane >> 4;
  int bh = blockIdx.y;
  int q0 = blockIdx.x * 128 + w * 16;
  const size_t base = (size_t)bh * SEQ * HD;
  const short* Kg = kn + base;
  const short* Vg = vt + base;

  bf16x8 qf[4];
#pragma unroll
  for (int kf = 0; kf < 4; ++kf)
    qf[kf] = *(const bf16x8*)&qn[base + (size_t)(q0 + c) * HD + kf * 32 + g * 8];

  f32x4 acc[8] = {};
  float m_ = -1e30f, l_ = 0.f;

  // staging: 16 K-chunks + 16 V-chunks of 1KB; wave w stages chunks {2w, 2w+1}
  int ksrc[2], vsrc[2];
#pragma unroll
  for (int p = 0; p < 2; ++p) {
    int ch = w * 2 + p;
    int o = ch * 1024 + lane * 16;                   // linear LDS byte offset
    int kr = o >> 8, kc = o & 255;                   // K: 256B rows
    ksrc[p] = kr * HD + ((kc ^ ((kr & 7) << 4)) >> 1);
    int vr = o >> 7, vc = o & 127;                   // V: 128B rows
    vsrc[p] = vr * SEQ + ((vc ^ ((vr & 7) << 4)) >> 1);
  }
  // read offsets (bytes), loop-invariant
  int swz = (c & 7) << 4;
  int koff[4], voff[4];
#pragma unroll
  for (int kf = 0; kf < 4; ++kf) koff[kf] = c * 256 + ((kf * 64 + g * 16) ^ swz);
#pragma unroll
  for (int kt = 0; kt < 4; ++kt) voff[kt] = c * 128 + ((kt * 32 + g * 8) ^ swz);

  // prologue: stage tile 0 into buffer 0
#pragma unroll
  for (int p = 0; p < 2; ++p) {
    int ch = w * 2 + p;
    gload_lds16(Kg + ksrc[p], (char*)&Ks[0][0] + ch * 1024);
    gload_lds16(Vg + vsrc[p], (char*)&Vs[0][0] + ch * 1024);
  }

  const int NT = SEQ / 64;
  for (int t = 0; t < NT; ++t) {
    int cur = t & 1;
    __syncthreads();           // vmcnt(0) drain => buf[cur] ready; buf[cur^1] free
    if (t + 1 < NT) {
      int k0n = (t + 1) * 64;
#pragma unroll
      for (int p = 0; p < 2; ++p) {
        int ch = w * 2 + p;
        gload_lds16(Kg + (size_t)k0n * HD + ksrc[p], (char*)&Ks[cur ^ 1][0] + ch * 1024);
        gload_lds16(Vg + k0n + vsrc[p],              (char*)&Vs[cur ^ 1][0] + ch * 1024);
      }
    }
    const char* Kb = (const char*)&Ks[cur][0];
    const char* Vb = (const char*)&Vs[cur][0];

    // QK^T (swapped): s[kt] lane(c,g)[i] = S[kt*16 + g*4 + i][q0 + c], log2 domain
    f32x4 s[4];
    __builtin_amdgcn_s_setprio(1);
#pragma unroll
    for (int kt = 0; kt < 4; ++kt) {
      f32x4 sa = {0.f, 0.f, 0.f, 0.f};
#pragma unroll
      for (int kf = 0; kf < 4; ++kf) {
        bf16x8 kb = *(const bf16x8*)(Kb + kt * 4096 + koff[kf]);
        sa = __builtin_amdgcn_mfma_f32_16x16x32_bf16(kb, qf[kf], sa, 0, 0, 0);
      }
      s[kt] = sa;
    }
    __builtin_amdgcn_s_setprio(0);

    // per-lane scalar online softmax (q = c)
    float pmax = -1e30f;
#pragma unroll
    for (int kt = 0; kt < 4; ++kt)
#pragma unroll
      for (int i = 0; i < 4; ++i) pmax = fmaxf(pmax, s[kt][i]);
    pmax = fmaxf(pmax, __shfl_xor(pmax, 16));
    pmax = fmaxf(pmax, __shfl_xor(pmax, 32));
    if (!__all(pmax <= m_ + 11.5f)) {   // defer-max: p bounded by 2^11.5
      float mn = fmaxf(m_, pmax);
      float al = exp2fast(m_ - mn);
      m_ = mn; l_ *= al;
#pragma unroll
      for (int db = 0; db < 8; ++db)
#pragma unroll
        for (int i = 0; i < 4; ++i) acc[db][i] *= al;
    }
    float r = 0.f;
#pragma unroll
    for (int kt = 0; kt < 4; ++kt)
#pragma unroll
      for (int i = 0; i < 4; ++i) {
        float p = exp2fast(s[kt][i] - m_);
        r += p; s[kt][i] = p;
      }
    r += __shfl_xor(r, 16);
    r += __shfl_xor(r, 32);
    l_ += r;

    // pack P to bf16 in-register: pb[kt] = B-fragment of mfma16 (P[k][q=c])
    bf16x4 pb[4];
#pragma unroll
    for (int kt = 0; kt < 4; ++kt) {
      u32x2 tpk;
      tpk[0] = cvt_pk_bf16(s[kt][0], s[kt][1]);
      tpk[1] = cvt_pk_bf16(s[kt][2], s[kt][3]);
      pb[kt] = __builtin_bit_cast(bf16x4, tpk);
    }

    // PV: acc[db] += Vt-frag x pb  (16x16x16)
    __builtin_amdgcn_s_setprio(1);
#pragma unroll
    for (int kt = 0; kt < 4; ++kt)
#pragma unroll
      for (int db = 0; db < 8; ++db) {
        bf16x4 va = *(const bf16x4*)(Vb + db * 2048 + voff[kt]);
        acc[db] = mfma16(va, pb[kt], acc[db]);
      }
    __builtin_amdgcn_s_setprio(0);
  }
#if MFMA16_ASM
  asm volatile("s_nop 7\n\ts_nop 7");
#endif

  int b = bh >> 4, h = bh & 15;
  float linv = 1.f / l_;
#pragma unroll
  for (int db = 0; db < 8; ++db) {
    short4 o;
    o.x = f2bf(acc[db][0] * linv);
    o.y = f2bf(acc[db][1] * linv);
    o.z = f2bf(acc[db][2] * linv);
    o.w = f2bf(acc[db][3] * linv);
    *(short4*)&attn[(size_t)(b * SEQ + q0 + c) * D_MODEL + h * HD + db * 16 + g * 4] = o;
  }
}

// ---------------- launch ----------------
extern "C" void kernel_launch(void* const* d_in, const int* in_sizes, int n_in,
                              void* d_out, int out_size, void* d_ws, size_t ws_size,
                              hipStream_t stream) {
  const float* hs   = (const float*)d_in[0];
  const float* fcos = (const float*)d_in[1];
  const float* fsin = (const float*)d_in[2];
  const float* Wq   = (const float*)d_in[3];
  const float* Wk   = (const float*)d_in[4];
  const float* Wv   = (const float*)d_in[5];
  const float* Wo   = (const float*)d_in[6];
  const float* gq   = (const float*)d_in[7];
  const float* gk   = (const float*)d_in[8];

  char* ws = (char*)d_ws;
  short* hs16  = (short*)ws;                        // 16,777,216 B
  short* Wt    = (short*)(ws + 16777216);           // 33,554,432 B (4 matrices, N-major)
  short* qkv16 = (short*)(ws + 50331648);           // 50,331,648 B (q,k,v bf16 token-major)
  short* qn    = (short*)(ws + 100663296);          // 16,777,216 B (B,H,S,128)
  short* kn    = (short*)(ws + 117440512);          // 16,777,216 B
  short* vt    = (short*)(ws + 134217728);          // 16,777,216 B (B,H,128,S)
  short* attn16 = qkv16;  // reuse q slot (dead after norm_rope)

  cast_bf16<<<8192, 256, 0, stream>>>(hs, hs16, NTOK * D_MODEL / 4);
  wtrans<<<dim3(32, 32, 4), 256, 0, stream>>>(Wq, Wk, Wv, Wo, Wt);
  gemm_bt<true><<<dim3(16, 32, 3), 256, 0, stream>>>(hs16, Wt, qkv16,
                                                     NTOK, D_MODEL, D_MODEL);
  norm_rope<<<dim3(16384, 2), 256, 0, stream>>>(qkv16, fcos, fsin, gq, gk, qn, kn);
  vtrans<<<dim3(32, 32), 256, 0, stream>>>(qkv16 + (size_t)2 * NTOK * D_MODEL, vt);
  flash<<<dim3(16, 32), 512, 0, stream>>>(qn, kn, vt, attn16);
  gemm_bt<false><<<dim3(16, 32, 1), 256, 0, stream>>>(attn16,
                                                      Wt + (size_t)3 * D_MODEL * D_MODEL,
                                                      d_out, NTOK, D_MODEL, D_MODEL);
}

// Round 7
// 316.917 us; speedup vs baseline: 1.1196x; 1.1191x over previous
//
#include <hip/hip_runtime.h>
#include <hip/hip_bf16.h>

typedef __attribute__((ext_vector_type(8))) short bf16x8;
typedef __attribute__((ext_vector_type(4))) short bf16x4;
typedef __attribute__((ext_vector_type(4))) float f32x4;
typedef __attribute__((ext_vector_type(4))) int   i32x4;
typedef __attribute__((ext_vector_type(2))) unsigned u32x2;

#define D_MODEL 2048
#define NTOK    4096   // B*S
#define NH      16
#define HD      128
#define SEQ     2048
#define NQKV    6144   // 3*D_MODEL (concatenated q,k,v outputs)

__device__ __forceinline__ short f2bf(float f) {
  unsigned u = __builtin_bit_cast(unsigned, f);
  unsigned r = u + 0x7FFFu + ((u >> 16) & 1u);   // RNE
  return (short)(r >> 16);
}
__device__ __forceinline__ float bf2f(short s) {
  return __builtin_bit_cast(float, ((unsigned)(unsigned short)s) << 16);
}

__device__ __forceinline__ float exp2fast(float x) {
#if __has_builtin(__builtin_amdgcn_exp2f)
  return __builtin_amdgcn_exp2f(x);
#else
  return exp2f(x);
#endif
}

// pack 2 fp32 -> 2 bf16 (RNE) in one instr
__device__ __forceinline__ unsigned cvt_pk_bf16(float a, float b) {
  unsigned r;
  asm("v_cvt_pk_bf16_f32 %0, %1, %2" : "=v"(r) : "v"(a), "v"(b));
  return r;
}

#if __has_builtin(__builtin_amdgcn_mfma_f32_16x16x16bf16_1k)
#define MFMA16_ASM 0
__device__ __forceinline__ f32x4 mfma16(bf16x4 a, bf16x4 b, f32x4 c) {
  return __builtin_amdgcn_mfma_f32_16x16x16bf16_1k(a, b, c, 0, 0, 0);
}
#else
#define MFMA16_ASM 1
__device__ __forceinline__ f32x4 mfma16(bf16x4 a, bf16x4 b, f32x4 c) {
  asm("s_nop 3\n\tv_mfma_f32_16x16x16_bf16 %0, %1, %2, %0" : "+v"(c) : "v"(a), "v"(b));
  return c;
}
#endif

// async global->LDS, 16B per lane. LDS dst must be wave-uniform; HW writes lane i at dst + i*16.
__device__ __forceinline__ void gload_lds16(const void* g, void* l) {
  typedef __attribute__((address_space(1))) const unsigned gu32;
  typedef __attribute__((address_space(3))) unsigned lu32;
  __builtin_amdgcn_global_load_lds((gu32*)(uintptr_t)g,
                                   (lu32*)(unsigned)(uintptr_t)l, 16, 0, 0);
}

// ---------------- 1. fp32 -> bf16 cast (vectorized) ----------------
__global__ __launch_bounds__(256) void cast_bf16(const float* __restrict__ in,
                                                 short* __restrict__ out, int n4) {
  int i = blockIdx.x * 256 + threadIdx.x;
  if (i >= n4) return;
  float4 v = ((const float4*)in)[i];
  short4 o;
  o.x = f2bf(v.x); o.y = f2bf(v.y); o.z = f2bf(v.z); o.w = f2bf(v.w);
  ((short4*)out)[i] = o;
}

// ---------------- 2. W (KxN) -> W^T (NxK) bf16, LDS-tiled ----------------
__global__ __launch_bounds__(256) void wtrans(const float* __restrict__ w0,
                                              const float* __restrict__ w1,
                                              const float* __restrict__ w2,
                                              const float* __restrict__ w3,
                                              short* __restrict__ wt) {
  int z = blockIdx.z;
  const float* W = (z == 0) ? w0 : (z == 1) ? w1 : (z == 2) ? w2 : w3;
  short* O = wt + (size_t)z * D_MODEL * D_MODEL;
  int n0 = blockIdx.x * 64, k0 = blockIdx.y * 64;
  __shared__ short T[64 * 136];
  int tid = threadIdx.x;
#pragma unroll
  for (int it = 0; it < 4; ++it) {
    int f = it * 256 + tid, kk = f >> 4, nc = f & 15;
    float4 v = *(const float4*)&W[(size_t)(k0 + kk) * D_MODEL + n0 + nc * 4];
    short4 o;
    o.x = f2bf(v.x); o.y = f2bf(v.y); o.z = f2bf(v.z); o.w = f2bf(v.w);
    *(short4*)&T[kk * 136 + nc * 4] = o;
  }
  __syncthreads();
#pragma unroll
  for (int it = 0; it < 4; ++it) {
    int u = it * 256 + tid, nn = u >> 4, kc = u & 15;
    short4 o;
    o.x = T[(kc * 4 + 0) * 136 + nn];
    o.y = T[(kc * 4 + 1) * 136 + nn];
    o.z = T[(kc * 4 + 2) * 136 + nn];
    o.w = T[(kc * 4 + 3) * 136 + nn];
    *(short4*)&O[(size_t)(n0 + nn) * D_MODEL + k0 + kc * 4] = o;
  }
}

// ---------------- 3/7. GEMM: 256x128 tile, BK=32, 4-deep LDS pipeline, counted vmcnt ----------------
// C[M, CS] = A[M, 2048] * Bt[N, 2048]^T  (CS = N = C row stride)
// 8 waves (4m x 2n), wave tile 64x64, acc 4x4 frags.
// LDS: 4 buffers x (A 16KB + B 8KB) = 96KB, XOR-swizzled (o ^= ((o>>7)&7)<<4).
// Pipeline: stage jt+3 | ds_read jt | 16 MFMA | vmcnt(6) | s_barrier  (never vmcnt(0) in main loop)
template <bool OUTBF16>
__global__ __launch_bounds__(512, 2) void gemm8(const short* __restrict__ A,
                                                const short* __restrict__ Bt,
                                                void* __restrict__ Cv, int CS) {
  __shared__ short L[4 * 12288];   // 98304 B
  int tid = threadIdx.x, w = tid >> 6, lane = tid & 63, c = lane & 15, g = lane >> 4;

  // supertile(4x4) + XCD-chunk block swizzle (bijective; requires gx%4==0, gy%4==0, (gx*gy)%128==0)
  int gx = gridDim.x, gy = gridDim.y;
  int lin = blockIdx.x + gx * blockIdx.y;
  int idx = lin >> 3, nst = (gx * gy) >> 7;
  int s = (lin & 7) * nst + (idx >> 4);
  int w16 = idx & 15;
  int smR = gy >> 2;
  int mblk = (s % smR) * 4 + (w16 >> 2);
  int nblk = (s / smR) * 4 + (w16 & 3);
  int m0 = mblk * 256, n0 = nblk * 128;
  int wm = w >> 1, wn = w & 1;

  const int NKT = D_MODEL / 32;   // 64 K-tiles

  // staging source offsets (elements): A chunks {2w, 2w+1} of 16, B chunk {w} of 8
  int asrc[2], bsrc;
#pragma unroll
  for (int q = 0; q < 2; ++q) {
    int o = (2 * w + q) * 1024 + lane * 16;       // linear byte within A half (16KB)
    int os = o ^ (((o >> 7) & 7) << 4);           // involution -> logical position
    asrc[q] = (m0 + (os >> 6)) * D_MODEL + ((os & 63) >> 1);
  }
  {
    int o = w * 1024 + lane * 16;                 // linear byte within B half (8KB)
    int os = o ^ (((o >> 7) & 7) << 4);
    bsrc = (n0 + (os >> 6)) * D_MODEL + ((os & 63) >> 1);
  }

  // fragment read byte offsets (swizzled), loop-invariant
  int aoff[4], boff[4];
#pragma unroll
  for (int mi = 0; mi < 4; ++mi) {
    int r = wm * 64 + mi * 16 + c;
    int o = r * 64 + g * 16;
    aoff[mi] = o ^ (((o >> 7) & 7) << 4);
  }
#pragma unroll
  for (int ni = 0; ni < 4; ++ni) {
    int r = wn * 64 + ni * 16 + c;
    int o = r * 64 + g * 16;
    boff[ni] = 16384 + (o ^ (((o >> 7) & 7) << 4));
  }

  auto STAGE = [&](int jt) {
    int kk = jt * 32;
    char* base = (char*)L + (jt & 3) * 24576;
    gload_lds16(A + asrc[0] + kk, base + (2 * w) * 1024);
    gload_lds16(A + asrc[1] + kk, base + (2 * w + 1) * 1024);
    gload_lds16(Bt + bsrc + kk, base + 16384 + w * 1024);
  };

  f32x4 acc[4][4] = {};

  STAGE(0); STAGE(1); STAGE(2);                    // 9 loads in flight
  asm volatile("s_waitcnt vmcnt(6)" ::: "memory"); // tile 0 landed
  __builtin_amdgcn_s_barrier();
  asm volatile("" ::: "memory");

  for (int jt = 0; jt < NKT; ++jt) {
    if (jt + 3 < NKT) STAGE(jt + 3);
    const char* buf = (const char*)L + (jt & 3) * 24576;
    bf16x8 af[4], bfv[4];
#pragma unroll
    for (int mi = 0; mi < 4; ++mi) af[mi] = *(const bf16x8*)(buf + aoff[mi]);
#pragma unroll
    for (int ni = 0; ni < 4; ++ni) bfv[ni] = *(const bf16x8*)(buf + boff[ni]);
    __builtin_amdgcn_s_setprio(1);
#pragma unroll
    for (int mi = 0; mi < 4; ++mi)
#pragma unroll
      for (int ni = 0; ni < 4; ++ni)
        acc[mi][ni] = __builtin_amdgcn_mfma_f32_16x16x32_bf16(af[mi], bfv[ni],
                                                              acc[mi][ni], 0, 0, 0);
    __builtin_amdgcn_s_setprio(0);
    if (jt + 1 < NKT) {
      // before the barrier, guarantee tile jt+1 landed; tiles {jt+2, jt+3} (3 loads each) may fly
      if (jt + 4 <= NKT - 1)      { asm volatile("s_waitcnt vmcnt(6)" ::: "memory"); }
      else if (jt + 3 <= NKT - 1) { asm volatile("s_waitcnt vmcnt(6)" ::: "memory"); }
      else if (jt + 2 <= NKT - 1) { asm volatile("s_waitcnt vmcnt(3)" ::: "memory"); }
      else                        { asm volatile("s_waitcnt vmcnt(0)" ::: "memory"); }
      __builtin_amdgcn_s_barrier();
      asm volatile("" ::: "memory");
    }
  }

  int row0 = m0 + wm * 64, col0 = n0 + wn * 64;
  if (OUTBF16) {
    short* Cb = (short*)Cv;
#pragma unroll
    for (int mi = 0; mi < 4; ++mi)
#pragma unroll
      for (int ni = 0; ni < 4; ++ni)
#pragma unroll
        for (int i = 0; i < 4; ++i)
          Cb[(size_t)(row0 + mi * 16 + g * 4 + i) * CS + col0 + ni * 16 + c] =
              f2bf(acc[mi][ni][i]);
  } else {
    float* Cf = (float*)Cv;
#pragma unroll
    for (int mi = 0; mi < 4; ++mi)
#pragma unroll
      for (int ni = 0; ni < 4; ++ni)
#pragma unroll
        for (int i = 0; i < 4; ++i)
          Cf[(size_t)(row0 + mi * 16 + g * 4 + i) * CS + col0 + ni * 16 + c] =
              acc[mi][ni][i];
  }
}

// ---------------- 4. fused RMSNorm + RoPE (q,k), one wave per (token,head) ----------------
// qkv16 layout: [token][6144] = [q 2048 | k 2048 | v 2048]
__global__ __launch_bounds__(256) void norm_rope(const short* __restrict__ qkv16,
                                                 const float* __restrict__ cosb,
                                                 const float* __restrict__ sinb,
                                                 const float* __restrict__ gq,
                                                 const float* __restrict__ gk,
                                                 short* __restrict__ qn,
                                                 short* __restrict__ kn) {
  int z = blockIdx.y;  // 0=q, 1=k
  const float* gg = z ? gk : gq;
  short* O = z ? kn : qn;
  int w = threadIdx.x >> 6, lane = threadIdx.x & 63;
  int p = blockIdx.x * 4 + w;          // (token,head) pair
  int token = p >> 4, h = p & 15;
  int v = *(const int*)&qkv16[(size_t)token * NQKV + z * D_MODEL + h * HD + lane * 2];
  float x0 = bf2f((short)(v & 0xffff));
  float x1 = bf2f((short)((unsigned)v >> 16));
  float ss = x0 * x0 + x1 * x1;
#pragma unroll
  for (int mk = 32; mk; mk >>= 1) ss += __shfl_xor(ss, mk);
  float rs = rsqrtf(ss * (1.f / 128.f) + 1e-5f);
  float qs = z ? 1.0f : 0.12751744f;   // 1/sqrt(128) * log2(e) for Q only
  rs *= qs;
  float xr = x0 * rs * gg[lane * 2];
  float xi = x1 * rs * gg[lane * 2 + 1];
  float cc = cosb[(size_t)token * 64 + lane];
  float sn = sinb[(size_t)token * 64 + lane];
  float or_ = xr * cc - xi * sn;
  float oi_ = xr * sn + xi * cc;
  int b = token >> 11, sidx = token & 2047;
  size_t dst = ((size_t)(b * NH + h) * SEQ + sidx) * HD + lane * 2;
  unsigned pk = (unsigned)(unsigned short)f2bf(or_) |
                ((unsigned)(unsigned short)f2bf(oi_) << 16);
  *(unsigned*)&O[dst] = pk;
}

// ---------------- 5. V (from qkv16 [token][6144], v at +4096) -> V^T (B,H,128,S) ----------------
__global__ __launch_bounds__(256) void vtrans(const short* __restrict__ qkv16,
                                              short* __restrict__ vt) {
  int st = blockIdx.x, bh = blockIdx.y;
  int b = bh >> 4, h = bh & 15;
  int t0 = b * SEQ + st * 64;
  __shared__ short Lt[64 * 136];
  int tid = threadIdx.x;
#pragma unroll
  for (int it = 0; it < 4; ++it) {
    int f = it * 256 + tid, tk = f >> 4, ch = f & 15;
    *(i32x4*)&Lt[tk * 136 + ch * 8] =
        *(const i32x4*)&qkv16[(size_t)(t0 + tk) * NQKV + 2 * D_MODEL + h * HD + ch * 8];
  }
  __syncthreads();
#pragma unroll
  for (int it = 0; it < 4; ++it) {
    int u = it * 256 + tid, d = u >> 3, kg = u & 7;
    bf16x8 o;
#pragma unroll
    for (int j = 0; j < 8; ++j) o[j] = Lt[(kg * 8 + j) * 136 + d];
    *(bf16x8*)&vt[(size_t)(bh * HD + d) * SEQ + st * 64 + kg * 8] = o;
  }
}

// ---------------- 6. flash attention: swapped QK^T, in-register P, scalar softmax state ----------------
__global__ __launch_bounds__(512, 4) void flash(const short* __restrict__ qn,
                                                const short* __restrict__ kn,
                                                const short* __restrict__ vt,
                                                short* __restrict__ attn) {
  __shared__ short Ks[2][64 * 128];   // 2 x 16KB
  __shared__ short Vs[2][128 * 64];   // 2 x 16KB
  int tid = threadIdx.x, w = tid >> 6, lane = tid & 63, c = lane & 15, g = lane >> 4;
  int bh = blockIdx.y;
  int q0 = blockIdx.x * 128 + w * 16;
  const size_t base = (size_t)bh * SEQ * HD;
  const short* Kg = kn + base;
  const short* Vg = vt + base;

  bf16x8 qf[4];
#pragma unroll
  for (int kf = 0; kf < 4; ++kf)
    qf[kf] = *(const bf16x8*)&qn[base + (size_t)(q0 + c) * HD + kf * 32 + g * 8];

  f32x4 acc[8] = {};
  float m_ = -1e30f, l_ = 0.f;

  int ksrc[2], vsrc[2];
#pragma unroll
  for (int p = 0; p < 2; ++p) {
    int ch = w * 2 + p;
    int o = ch * 1024 + lane * 16;                   // linear LDS byte offset
    int kr = o >> 8, kc = o & 255;                   // K: 256B rows
    ksrc[p] = kr * HD + ((kc ^ ((kr & 7) << 4)) >> 1);
    int vr = o >> 7, vc = o & 127;                   // V: 128B rows
    vsrc[p] = vr * SEQ + ((vc ^ ((vr & 7) << 4)) >> 1);
  }
  int swz = (c & 7) << 4;
  int koff[4], voff[4];
#pragma unroll
  for (int kf = 0; kf < 4; ++kf) koff[kf] = c * 256 + ((kf * 64 + g * 16) ^ swz);
#pragma unroll
  for (int kt = 0; kt < 4; ++kt) voff[kt] = c * 128 + ((kt * 32 + g * 8) ^ swz);

#pragma unroll
  for (int p = 0; p < 2; ++p) {
    int ch = w * 2 + p;
    gload_lds16(Kg + ksrc[p], (char*)&Ks[0][0] + ch * 1024);
    gload_lds16(Vg + vsrc[p], (char*)&Vs[0][0] + ch * 1024);
  }

  const int NT = SEQ / 64;
  for (int t = 0; t < NT; ++t) {
    int cur = t & 1;
    __syncthreads();           // vmcnt(0) drain => buf[cur] ready; buf[cur^1] free
    if (t + 1 < NT) {
      int k0n = (t + 1) * 64;
#pragma unroll
      for (int p = 0; p < 2; ++p) {
        int ch = w * 2 + p;
        gload_lds16(Kg + (size_t)k0n * HD + ksrc[p], (char*)&Ks[cur ^ 1][0] + ch * 1024);
        gload_lds16(Vg + k0n + vsrc[p],              (char*)&Vs[cur ^ 1][0] + ch * 1024);
      }
    }
    const char* Kb = (const char*)&Ks[cur][0];
    const char* Vb = (const char*)&Vs[cur][0];

    f32x4 s[4];
    __builtin_amdgcn_s_setprio(1);
#pragma unroll
    for (int kt = 0; kt < 4; ++kt) {
      f32x4 sa = {0.f, 0.f, 0.f, 0.f};
#pragma unroll
      for (int kf = 0; kf < 4; ++kf) {
        bf16x8 kb = *(const bf16x8*)(Kb + kt * 4096 + koff[kf]);
        sa = __builtin_amdgcn_mfma_f32_16x16x32_bf16(kb, qf[kf], sa, 0, 0, 0);
      }
      s[kt] = sa;
    }
    __builtin_amdgcn_s_setprio(0);

    float pmax = -1e30f;
#pragma unroll
    for (int kt = 0; kt < 4; ++kt)
#pragma unroll
      for (int i = 0; i < 4; ++i) pmax = fmaxf(pmax, s[kt][i]);
    pmax = fmaxf(pmax, __shfl_xor(pmax, 16));
    pmax = fmaxf(pmax, __shfl_xor(pmax, 32));
    if (!__all(pmax <= m_ + 11.5f)) {   // defer-max: p bounded by 2^11.5
      float mn = fmaxf(m_, pmax);
      float al = exp2fast(m_ - mn);
      m_ = mn; l_ *= al;
#pragma unroll
      for (int db = 0; db < 8; ++db)
#pragma unroll
        for (int i = 0; i < 4; ++i) acc[db][i] *= al;
    }
    float r = 0.f;
#pragma unroll
    for (int kt = 0; kt < 4; ++kt)
#pragma unroll
      for (int i = 0; i < 4; ++i) {
        float p = exp2fast(s[kt][i] - m_);
        r += p; s[kt][i] = p;
      }
    r += __shfl_xor(r, 16);
    r += __shfl_xor(r, 32);
    l_ += r;

    bf16x4 pb[4];
#pragma unroll
    for (int kt = 0; kt < 4; ++kt) {
      u32x2 tpk;
      tpk[0] = cvt_pk_bf16(s[kt][0], s[kt][1]);
      tpk[1] = cvt_pk_bf16(s[kt][2], s[kt][3]);
      pb[kt] = __builtin_bit_cast(bf16x4, tpk);
    }

    __builtin_amdgcn_s_setprio(1);
#pragma unroll
    for (int kt = 0; kt < 4; ++kt)
#pragma unroll
      for (int db = 0; db < 8; ++db) {
        bf16x4 va = *(const bf16x4*)(Vb + db * 2048 + voff[kt]);
        acc[db] = mfma16(va, pb[kt], acc[db]);
      }
    __builtin_amdgcn_s_setprio(0);
  }
#if MFMA16_ASM
  asm volatile("s_nop 7\n\ts_nop 7");
#endif

  int b = bh >> 4, h = bh & 15;
  float linv = 1.f / l_;
#pragma unroll
  for (int db = 0; db < 8; ++db) {
    short4 o;
    o.x = f2bf(acc[db][0] * linv);
    o.y = f2bf(acc[db][1] * linv);
    o.z = f2bf(acc[db][2] * linv);
    o.w = f2bf(acc[db][3] * linv);
    *(short4*)&attn[(size_t)(b * SEQ + q0 + c) * D_MODEL + h * HD + db * 16 + g * 4] = o;
  }
}

// ---------------- launch ----------------
extern "C" void kernel_launch(void* const* d_in, const int* in_sizes, int n_in,
                              void* d_out, int out_size, void* d_ws, size_t ws_size,
                              hipStream_t stream) {
  const float* hs   = (const float*)d_in[0];
  const float* fcos = (const float*)d_in[1];
  const float* fsin = (const float*)d_in[2];
  const float* Wq   = (const float*)d_in[3];
  const float* Wk   = (const float*)d_in[4];
  const float* Wv   = (const float*)d_in[5];
  const float* Wo   = (const float*)d_in[6];
  const float* gq   = (const float*)d_in[7];
  const float* gk   = (const float*)d_in[8];

  char* ws = (char*)d_ws;
  short* hs16  = (short*)ws;                        // 16,777,216 B (reused as attn16 later)
  short* Wt    = (short*)(ws + 16777216);           // 33,554,432 B ([Wq|Wk|Wv|Wo] N-major)
  short* qkv16 = (short*)(ws + 50331648);           // 50,331,648 B ([token][6144])
  short* qn    = (short*)(ws + 100663296);          // 16,777,216 B (B,H,S,128)
  short* kn    = (short*)(ws + 117440512);          // 16,777,216 B
  short* vt    = (short*)(ws + 134217728);          // 16,777,216 B (B,H,128,S)
  short* attn16 = hs16;  // hs16 dead after QKV GEMM

  cast_bf16<<<8192, 256, 0, stream>>>(hs, hs16, NTOK * D_MODEL / 4);
  wtrans<<<dim3(32, 32, 4), 256, 0, stream>>>(Wq, Wk, Wv, Wo, Wt);
  // QKV: M=4096 x N=6144, grid 48x16 = 768 blocks (3.0 waves)
  gemm8<true><<<dim3(48, 16), 512, 0, stream>>>(hs16, Wt, qkv16, NQKV);
  norm_rope<<<dim3(16384, 2), 256, 0, stream>>>(qkv16, fcos, fsin, gq, gk, qn, kn);
  vtrans<<<dim3(32, 32), 256, 0, stream>>>(qkv16, vt);
  flash<<<dim3(16, 32), 512, 0, stream>>>(qn, kn, vt, attn16);
  // Wo: M=4096 x N=2048, grid 16x16 = 256 blocks (1.0 wave)
  gemm8<false><<<dim3(16, 16), 512, 0, stream>>>(attn16,
                                                 Wt + (size_t)3 * D_MODEL * D_MODEL,
                                                 d_out, D_MODEL);
}

// Round 8
// 283.087 us; speedup vs baseline: 1.2534x; 1.1195x over previous
//
#include <hip/hip_runtime.h>
#include <hip/hip_bf16.h>

typedef __attribute__((ext_vector_type(8))) short bf16x8;
typedef __attribute__((ext_vector_type(4))) short bf16x4;
typedef __attribute__((ext_vector_type(4))) float f32x4;
typedef __attribute__((ext_vector_type(16))) float f32x16;
typedef __attribute__((ext_vector_type(4))) int   i32x4;
typedef __attribute__((ext_vector_type(2))) unsigned u32x2;
typedef __attribute__((ext_vector_type(4))) unsigned u32x4;

#define D_MODEL 2048
#define NTOK    4096   // B*S
#define NH      16
#define HD      128
#define SEQ     2048
#define NQKV    6144   // 3*D_MODEL (concatenated q,k,v outputs)

__device__ __forceinline__ short f2bf(float f) {
  unsigned u = __builtin_bit_cast(unsigned, f);
  unsigned r = u + 0x7FFFu + ((u >> 16) & 1u);   // RNE
  return (short)(r >> 16);
}
__device__ __forceinline__ float bf2f(short s) {
  return __builtin_bit_cast(float, ((unsigned)(unsigned short)s) << 16);
}

__device__ __forceinline__ float exp2fast(float x) {
#if __has_builtin(__builtin_amdgcn_exp2f)
  return __builtin_amdgcn_exp2f(x);
#else
  return exp2f(x);
#endif
}

// pack 2 fp32 -> 2 bf16 (RNE) in one instr
__device__ __forceinline__ unsigned cvt_pk_bf16(float a, float b) {
  unsigned r;
  asm("v_cvt_pk_bf16_f32 %0, %1, %2" : "=v"(r) : "v"(a), "v"(b));
  return r;
}

// exchange: x.hi-lanes <-> y.lo-lanes. After: x = {x.lo, y.lo}, y = {x.hi, y.hi}
__device__ __forceinline__ void permswap(unsigned& x, unsigned& y) {
#if __has_builtin(__builtin_amdgcn_permlane32_swap)
  u32x2 r = __builtin_amdgcn_permlane32_swap(x, y, false, false);
  x = r[0]; y = r[1];
#else
  asm volatile("v_permlane32_swap_b32 %0, %1" : "+v"(x), "+v"(y));
#endif
}

__device__ __forceinline__ f32x16 mfma32(bf16x8 a, bf16x8 b, f32x16 c) {
  return __builtin_amdgcn_mfma_f32_32x32x16_bf16(a, b, c, 0, 0, 0);
}

// async global->LDS, 16B per lane. LDS dst must be wave-uniform; HW writes lane i at dst + i*16.
__device__ __forceinline__ void gload_lds16(const void* g, void* l) {
  typedef __attribute__((address_space(1))) const unsigned gu32;
  typedef __attribute__((address_space(3))) unsigned lu32;
  __builtin_amdgcn_global_load_lds((gu32*)(uintptr_t)g,
                                   (lu32*)(unsigned)(uintptr_t)l, 16, 0, 0);
}

// ---------------- 1. fp32 -> bf16 cast (vectorized) ----------------
__global__ __launch_bounds__(256) void cast_bf16(const float* __restrict__ in,
                                                 short* __restrict__ out, int n4) {
  int i = blockIdx.x * 256 + threadIdx.x;
  if (i >= n4) return;
  float4 v = ((const float4*)in)[i];
  short4 o;
  o.x = f2bf(v.x); o.y = f2bf(v.y); o.z = f2bf(v.z); o.w = f2bf(v.w);
  ((short4*)out)[i] = o;
}

// ---------------- 2. W (KxN) -> W^T (NxK) bf16, LDS-tiled ----------------
__global__ __launch_bounds__(256) void wtrans(const float* __restrict__ w0,
                                              const float* __restrict__ w1,
                                              const float* __restrict__ w2,
                                              const float* __restrict__ w3,
                                              short* __restrict__ wt) {
  int z = blockIdx.z;
  const float* W = (z == 0) ? w0 : (z == 1) ? w1 : (z == 2) ? w2 : w3;
  short* O = wt + (size_t)z * D_MODEL * D_MODEL;
  int n0 = blockIdx.x * 64, k0 = blockIdx.y * 64;
  __shared__ short T[64 * 136];
  int tid = threadIdx.x;
#pragma unroll
  for (int it = 0; it < 4; ++it) {
    int f = it * 256 + tid, kk = f >> 4, nc = f & 15;
    float4 v = *(const float4*)&W[(size_t)(k0 + kk) * D_MODEL + n0 + nc * 4];
    short4 o;
    o.x = f2bf(v.x); o.y = f2bf(v.y); o.z = f2bf(v.z); o.w = f2bf(v.w);
    *(short4*)&T[kk * 136 + nc * 4] = o;
  }
  __syncthreads();
#pragma unroll
  for (int it = 0; it < 4; ++it) {
    int u = it * 256 + tid, nn = u >> 4, kc = u & 15;
    short4 o;
    o.x = T[(kc * 4 + 0) * 136 + nn];
    o.y = T[(kc * 4 + 1) * 136 + nn];
    o.z = T[(kc * 4 + 2) * 136 + nn];
    o.w = T[(kc * 4 + 3) * 136 + nn];
    *(short4*)&O[(size_t)(n0 + nn) * D_MODEL + k0 + kc * 4] = o;
  }
}

// ---------------- 3/7. GEMM: 256x128 tile, BK=32, 4-deep LDS pipeline, counted vmcnt ----------------
template <bool OUTBF16>
__global__ __launch_bounds__(512, 2) void gemm8(const short* __restrict__ A,
                                                const short* __restrict__ Bt,
                                                void* __restrict__ Cv, int CS) {
  __shared__ short L[4 * 12288];   // 98304 B
  int tid = threadIdx.x, w = tid >> 6, lane = tid & 63, c = lane & 15, g = lane >> 4;

  int gx = gridDim.x, gy = gridDim.y;
  int lin = blockIdx.x + gx * blockIdx.y;
  int idx = lin >> 3, nst = (gx * gy) >> 7;
  int s = (lin & 7) * nst + (idx >> 4);
  int w16 = idx & 15;
  int smR = gy >> 2;
  int mblk = (s % smR) * 4 + (w16 >> 2);
  int nblk = (s / smR) * 4 + (w16 & 3);
  int m0 = mblk * 256, n0 = nblk * 128;
  int wm = w >> 1, wn = w & 1;

  const int NKT = D_MODEL / 32;   // 64 K-tiles

  int asrc[2], bsrc;
#pragma unroll
  for (int q = 0; q < 2; ++q) {
    int o = (2 * w + q) * 1024 + lane * 16;
    int os = o ^ (((o >> 7) & 7) << 4);
    asrc[q] = (m0 + (os >> 6)) * D_MODEL + ((os & 63) >> 1);
  }
  {
    int o = w * 1024 + lane * 16;
    int os = o ^ (((o >> 7) & 7) << 4);
    bsrc = (n0 + (os >> 6)) * D_MODEL + ((os & 63) >> 1);
  }

  int aoff[4], boff[4];
#pragma unroll
  for (int mi = 0; mi < 4; ++mi) {
    int r = wm * 64 + mi * 16 + c;
    int o = r * 64 + g * 16;
    aoff[mi] = o ^ (((o >> 7) & 7) << 4);
  }
#pragma unroll
  for (int ni = 0; ni < 4; ++ni) {
    int r = wn * 64 + ni * 16 + c;
    int o = r * 64 + g * 16;
    boff[ni] = 16384 + (o ^ (((o >> 7) & 7) << 4));
  }

  auto STAGE = [&](int jt) {
    int kk = jt * 32;
    char* base = (char*)L + (jt & 3) * 24576;
    gload_lds16(A + asrc[0] + kk, base + (2 * w) * 1024);
    gload_lds16(A + asrc[1] + kk, base + (2 * w + 1) * 1024);
    gload_lds16(Bt + bsrc + kk, base + 16384 + w * 1024);
  };

  f32x4 acc[4][4] = {};

  STAGE(0); STAGE(1); STAGE(2);
  asm volatile("s_waitcnt vmcnt(6)" ::: "memory");
  __builtin_amdgcn_s_barrier();
  asm volatile("" ::: "memory");

  for (int jt = 0; jt < NKT; ++jt) {
    if (jt + 3 < NKT) STAGE(jt + 3);
    const char* buf = (const char*)L + (jt & 3) * 24576;
    bf16x8 af[4], bfv[4];
#pragma unroll
    for (int mi = 0; mi < 4; ++mi) af[mi] = *(const bf16x8*)(buf + aoff[mi]);
#pragma unroll
    for (int ni = 0; ni < 4; ++ni) bfv[ni] = *(const bf16x8*)(buf + boff[ni]);
    __builtin_amdgcn_s_setprio(1);
#pragma unroll
    for (int mi = 0; mi < 4; ++mi)
#pragma unroll
      for (int ni = 0; ni < 4; ++ni)
        acc[mi][ni] = __builtin_amdgcn_mfma_f32_16x16x32_bf16(af[mi], bfv[ni],
                                                              acc[mi][ni], 0, 0, 0);
    __builtin_amdgcn_s_setprio(0);
    if (jt + 1 < NKT) {
      if (jt + 3 <= NKT - 1)      { asm volatile("s_waitcnt vmcnt(6)" ::: "memory"); }
      else if (jt + 2 <= NKT - 1) { asm volatile("s_waitcnt vmcnt(3)" ::: "memory"); }
      else                        { asm volatile("s_waitcnt vmcnt(0)" ::: "memory"); }
      __builtin_amdgcn_s_barrier();
      asm volatile("" ::: "memory");
    }
  }

  int row0 = m0 + wm * 64, col0 = n0 + wn * 64;
  if (OUTBF16) {
    short* Cb = (short*)Cv;
#pragma unroll
    for (int mi = 0; mi < 4; ++mi)
#pragma unroll
      for (int ni = 0; ni < 4; ++ni)
#pragma unroll
        for (int i = 0; i < 4; ++i)
          Cb[(size_t)(row0 + mi * 16 + g * 4 + i) * CS + col0 + ni * 16 + c] =
              f2bf(acc[mi][ni][i]);
  } else {
    float* Cf = (float*)Cv;
#pragma unroll
    for (int mi = 0; mi < 4; ++mi)
#pragma unroll
      for (int ni = 0; ni < 4; ++ni)
#pragma unroll
        for (int i = 0; i < 4; ++i)
          Cf[(size_t)(row0 + mi * 16 + g * 4 + i) * CS + col0 + ni * 16 + c] =
              acc[mi][ni][i];
  }
}

// ---------------- 4. fused RMSNorm + RoPE (q,k), one wave per (token,head) ----------------
__global__ __launch_bounds__(256) void norm_rope(const short* __restrict__ qkv16,
                                                 const float* __restrict__ cosb,
                                                 const float* __restrict__ sinb,
                                                 const float* __restrict__ gq,
                                                 const float* __restrict__ gk,
                                                 short* __restrict__ qn,
                                                 short* __restrict__ kn) {
  int z = blockIdx.y;  // 0=q, 1=k
  const float* gg = z ? gk : gq;
  short* O = z ? kn : qn;
  int w = threadIdx.x >> 6, lane = threadIdx.x & 63;
  int p = blockIdx.x * 4 + w;          // (token,head) pair
  int token = p >> 4, h = p & 15;
  int v = *(const int*)&qkv16[(size_t)token * NQKV + z * D_MODEL + h * HD + lane * 2];
  float x0 = bf2f((short)(v & 0xffff));
  float x1 = bf2f((short)((unsigned)v >> 16));
  float ss = x0 * x0 + x1 * x1;
#pragma unroll
  for (int mk = 32; mk; mk >>= 1) ss += __shfl_xor(ss, mk);
  float rs = rsqrtf(ss * (1.f / 128.f) + 1e-5f);
  float qs = z ? 1.0f : 0.12751744f;   // 1/sqrt(128) * log2(e) for Q only
  rs *= qs;
  float xr = x0 * rs * gg[lane * 2];
  float xi = x1 * rs * gg[lane * 2 + 1];
  float cc = cosb[(size_t)token * 64 + lane];
  float sn = sinb[(size_t)token * 64 + lane];
  float or_ = xr * cc - xi * sn;
  float oi_ = xr * sn + xi * cc;
  int b = token >> 11, sidx = token & 2047;
  size_t dst = ((size_t)(b * NH + h) * SEQ + sidx) * HD + lane * 2;
  unsigned pk = (unsigned)(unsigned short)f2bf(or_) |
                ((unsigned)(unsigned short)f2bf(oi_) << 16);
  *(unsigned*)&O[dst] = pk;
}

// ---------------- 5. V (from qkv16 [token][6144], v at +4096) -> V^T (B,H,128,S) ----------------
__global__ __launch_bounds__(256) void vtrans(const short* __restrict__ qkv16,
                                              short* __restrict__ vt) {
  int st = blockIdx.x, bh = blockIdx.y;
  int b = bh >> 4, h = bh & 15;
  int t0 = b * SEQ + st * 64;
  __shared__ short Lt[64 * 136];
  int tid = threadIdx.x;
#pragma unroll
  for (int it = 0; it < 4; ++it) {
    int f = it * 256 + tid, tk = f >> 4, ch = f & 15;
    *(i32x4*)&Lt[tk * 136 + ch * 8] =
        *(const i32x4*)&qkv16[(size_t)(t0 + tk) * NQKV + 2 * D_MODEL + h * HD + ch * 8];
  }
  __syncthreads();
#pragma unroll
  for (int it = 0; it < 4; ++it) {
    int u = it * 256 + tid, d = u >> 3, kg = u & 7;
    bf16x8 o;
#pragma unroll
    for (int j = 0; j < 8; ++j) o[j] = Lt[(kg * 8 + j) * 136 + d];
    *(bf16x8*)&vt[(size_t)(bh * HD + d) * SEQ + st * 64 + kg * 8] = o;
  }
}

// ---------------- 6. flash attention: 8 waves x 32 q-rows, 32x32x16 MFMA ----------------
// QK^T: mfma32(K, Q) -> S C-layout: col q = lane&31, row k = kt*32 + (reg&3)+8*(reg>>2)+4*hi.
// P redistributed to B-frag via cvt_pk + permlane32_swap (one swap fills words w and w+2).
// PV: mfma32(V^T, P) -> acc[db]: d = db*32 + (reg&3)+8*(reg>>2)+4*hi, q = lane&31.
// K/V LDS: XOR-swizzled (phys = row*RB + (col ^ ((row&7)<<4))), gload_lds staged, dbuf.
__global__ __launch_bounds__(512, 2) void flash(const short* __restrict__ qn,
                                                const short* __restrict__ kn,
                                                const short* __restrict__ vt,
                                                short* __restrict__ attn) {
  __shared__ short Ks[2][64 * 128];   // 2 x 16KB, [key][d]
  __shared__ short Vs[2][128 * 64];   // 2 x 16KB, [d][key]
  int tid = threadIdx.x, w = tid >> 6, lane = tid & 63;
  int q31 = lane & 31, hi = lane >> 5;

  // XCD-aware remap: XCD (phys%8) gets 4 bh x 8 q-blocks -> K/V L2-resident per XCD
  int phys = blockIdx.x;
  int xcd = phys & 7, idx = phys >> 3;
  int bh = xcd * 4 + (idx >> 3);
  int qb = idx & 7;
  int q0 = qb * 256 + w * 32;

  const size_t base = (size_t)bh * SEQ * HD;
  const short* Kg = kn + base;
  const short* Vg = vt + base;

  // Q fragments (B-side): position (hi, j) <- Q[q0+q31][d = s*16 + hi*8 + j]
  bf16x8 qf[8];
#pragma unroll
  for (int s = 0; s < 8; ++s)
    qf[s] = *(const bf16x8*)&qn[base + (size_t)(q0 + q31) * HD + s * 16 + hi * 8];

  f32x16 acc[4] = {};
  float m_ = -1e30f, l_ = 0.f;

  // staging source offsets (same swizzle as reads)
  int ksrc[2], vsrc[2];
#pragma unroll
  for (int p = 0; p < 2; ++p) {
    int ch = w * 2 + p;
    int o = ch * 1024 + lane * 16;
    int kr = o >> 8, kc = o & 255;                   // K: 256B rows
    ksrc[p] = kr * HD + ((kc ^ ((kr & 7) << 4)) >> 1);
    int vr = o >> 7, vc = o & 127;                   // V: 128B rows
    vsrc[p] = vr * SEQ + ((vc ^ ((vr & 7) << 4)) >> 1);
  }
  // read offsets (bytes), loop-invariant; row&7 == q31&7 for all rows used
  int swz = (q31 & 7) << 4;
  int koff[8], voff[4];
#pragma unroll
  for (int kf = 0; kf < 8; ++kf) koff[kf] = (kf * 32 + hi * 16) ^ swz;
#pragma unroll
  for (int kk = 0; kk < 4; ++kk) voff[kk] = (kk * 32 + hi * 16) ^ swz;
  int krow0 = q31 * 256, krow1 = (32 + q31) * 256;

  // prologue: stage tile 0 into buffer 0
#pragma unroll
  for (int p = 0; p < 2; ++p) {
    int ch = w * 2 + p;
    gload_lds16(Kg + ksrc[p], (char*)&Ks[0][0] + ch * 1024);
    gload_lds16(Vg + vsrc[p], (char*)&Vs[0][0] + ch * 1024);
  }

  const int NT = SEQ / 64;
  for (int t = 0; t < NT; ++t) {
    int cur = t & 1;
    __syncthreads();           // vmcnt(0) drain => buf[cur] ready; buf[cur^1] free
    if (t + 1 < NT) {
      int k0n = (t + 1) * 64;
#pragma unroll
      for (int p = 0; p < 2; ++p) {
        int ch = w * 2 + p;
        gload_lds16(Kg + (size_t)k0n * HD + ksrc[p], (char*)&Ks[cur ^ 1][0] + ch * 1024);
        gload_lds16(Vg + k0n + vsrc[p],              (char*)&Vs[cur ^ 1][0] + ch * 1024);
      }
    }
    const char* Kb = (const char*)&Ks[cur][0];
    const char* Vb = (const char*)&Vs[cur][0];

    // QK^T: two 32x32 blocks (keys 0-31, 32-63), K=128 over 8 slices
    f32x16 s0 = {0,0,0,0,0,0,0,0,0,0,0,0,0,0,0,0};
    f32x16 s1 = {0,0,0,0,0,0,0,0,0,0,0,0,0,0,0,0};
    __builtin_amdgcn_s_setprio(1);
#pragma unroll
    for (int kf = 0; kf < 8; ++kf) {
      bf16x8 k0 = *(const bf16x8*)(Kb + krow0 + koff[kf]);
      s0 = mfma32(k0, qf[kf], s0);
      bf16x8 k1 = *(const bf16x8*)(Kb + krow1 + koff[kf]);
      s1 = mfma32(k1, qf[kf], s1);
    }
    __builtin_amdgcn_s_setprio(0);

    // per-lane scalar online softmax (q = q31); halves hold disjoint k's of same q
    float p0 = -1e30f, p1 = -1e30f, p2 = -1e30f, p3 = -1e30f;
#pragma unroll
    for (int i = 0; i < 4; ++i) {
      p0 = fmaxf(p0, fmaxf(s0[i], s0[i + 4]));
      p1 = fmaxf(p1, fmaxf(s0[i + 8], s0[i + 12]));
      p2 = fmaxf(p2, fmaxf(s1[i], s1[i + 4]));
      p3 = fmaxf(p3, fmaxf(s1[i + 8], s1[i + 12]));
    }
    float pmax = fmaxf(fmaxf(p0, p1), fmaxf(p2, p3));
    pmax = fmaxf(pmax, __shfl_xor(pmax, 32));
    if (!__all(pmax <= m_ + 11.5f)) {   // defer-max: p bounded by 2^11.5
      float mn = fmaxf(m_, pmax);
      float al = exp2fast(m_ - mn);
      m_ = mn; l_ *= al;
#pragma unroll
      for (int db = 0; db < 4; ++db)
#pragma unroll
        for (int i = 0; i < 16; ++i) acc[db][i] *= al;
    }
    float r0 = 0.f, r1 = 0.f;
#pragma unroll
    for (int i = 0; i < 16; ++i) {
      float pa = exp2fast(s0[i] - m_); r0 += pa; s0[i] = pa;
      float pb = exp2fast(s1[i] - m_); r1 += pb; s1[i] = pb;
    }
    float r = r0 + r1;
    r += __shfl_xor(r, 32);
    l_ += r;

    // pack P -> B-frags and PV. For chunk kk = kt*2+c2:
    //   x0=pk(s[c2*8+0],s[c2*8+1]) x1=pk(s[c2*8+2],s[c2*8+3])  (q4 = c2*2)
    //   y0=pk(s[c2*8+4],s[c2*8+5]) y1=pk(s[c2*8+6],s[c2*8+7])  (q4 = c2*2+1)
    //   permswap(x0,y0): x0 -> frag reg0 (j0,1), y0 -> reg2 (j4,5); likewise x1/y1 -> reg1/reg3
    __builtin_amdgcn_s_setprio(1);
#pragma unroll
    for (int kt = 0; kt < 2; ++kt) {
      const f32x16& sv = kt ? s1 : s0;
#pragma unroll
      for (int c2 = 0; c2 < 2; ++c2) {
        unsigned x0 = cvt_pk_bf16(sv[c2 * 8 + 0], sv[c2 * 8 + 1]);
        unsigned x1 = cvt_pk_bf16(sv[c2 * 8 + 2], sv[c2 * 8 + 3]);
        unsigned y0 = cvt_pk_bf16(sv[c2 * 8 + 4], sv[c2 * 8 + 5]);
        unsigned y1 = cvt_pk_bf16(sv[c2 * 8 + 6], sv[c2 * 8 + 7]);
        permswap(x0, y0);
        permswap(x1, y1);
        u32x4 pw = {x0, x1, y0, y1};
        bf16x8 pfrag = __builtin_bit_cast(bf16x8, pw);
        int vo = voff[kt * 2 + c2];
#pragma unroll
        for (int db = 0; db < 4; ++db) {
          bf16x8 va = *(const bf16x8*)(Vb + (db * 32 + q31) * 128 + vo);
          acc[db] = mfma32(va, pfrag, acc[db]);
        }
      }
    }
    __builtin_amdgcn_s_setprio(0);
  }

  int b = bh >> 4, h = bh & 15;
  float linv = 1.f / l_;
  size_t orow = (size_t)(b * SEQ + q0 + q31) * D_MODEL + h * HD;
#pragma unroll
  for (int db = 0; db < 4; ++db)
#pragma unroll
    for (int rg = 0; rg < 4; ++rg) {
      short4 o;
      o.x = f2bf(acc[db][rg * 4 + 0] * linv);
      o.y = f2bf(acc[db][rg * 4 + 1] * linv);
      o.z = f2bf(acc[db][rg * 4 + 2] * linv);
      o.w = f2bf(acc[db][rg * 4 + 3] * linv);
      *(short4*)&attn[orow + db * 32 + rg * 8 + hi * 4] = o;
    }
}

// ---------------- launch ----------------
extern "C" void kernel_launch(void* const* d_in, const int* in_sizes, int n_in,
                              void* d_out, int out_size, void* d_ws, size_t ws_size,
                              hipStream_t stream) {
  const float* hs   = (const float*)d_in[0];
  const float* fcos = (const float*)d_in[1];
  const float* fsin = (const float*)d_in[2];
  const float* Wq   = (const float*)d_in[3];
  const float* Wk   = (const float*)d_in[4];
  const float* Wv   = (const float*)d_in[5];
  const float* Wo   = (const float*)d_in[6];
  const float* gq   = (const float*)d_in[7];
  const float* gk   = (const float*)d_in[8];

  char* ws = (char*)d_ws;
  short* hs16  = (short*)ws;                        // 16,777,216 B (reused as attn16 later)
  short* Wt    = (short*)(ws + 16777216);           // 33,554,432 B ([Wq|Wk|Wv|Wo] N-major)
  short* qkv16 = (short*)(ws + 50331648);           // 50,331,648 B ([token][6144])
  short* qn    = (short*)(ws + 100663296);          // 16,777,216 B (B,H,S,128)
  short* kn    = (short*)(ws + 117440512);          // 16,777,216 B
  short* vt    = (short*)(ws + 134217728);          // 16,777,216 B (B,H,128,S)
  short* attn16 = hs16;  // hs16 dead after QKV GEMM

  cast_bf16<<<8192, 256, 0, stream>>>(hs, hs16, NTOK * D_MODEL / 4);
  wtrans<<<dim3(32, 32, 4), 256, 0, stream>>>(Wq, Wk, Wv, Wo, Wt);
  // QKV: M=4096 x N=6144, grid 48x16 = 768 blocks (3.0 waves)
  gemm8<true><<<dim3(48, 16), 512, 0, stream>>>(hs16, Wt, qkv16, NQKV);
  norm_rope<<<dim3(16384, 2), 256, 0, stream>>>(qkv16, fcos, fsin, gq, gk, qn, kn);
  vtrans<<<dim3(32, 32), 256, 0, stream>>>(qkv16, vt);
  flash<<<dim3(256), 512, 0, stream>>>(qn, kn, vt, attn16);
  // Wo: M=4096 x N=2048, grid 16x16 = 256 blocks (1.0 wave)
  gemm8<false><<<dim3(16, 16), 512, 0, stream>>>(attn16,
                                                 Wt + (size_t)3 * D_MODEL * D_MODEL,
                                                 d_out, D_MODEL);
}

// Round 9
// 273.803 us; speedup vs baseline: 1.2959x; 1.0339x over previous
//
#include <hip/hip_runtime.h>
#include <hip/hip_bf16.h>

typedef __attribute__((ext_vector_type(8))) short bf16x8;
typedef __attribute__((ext_vector_type(4))) short bf16x4;
typedef __attribute__((ext_vector_type(4))) float f32x4;
typedef __attribute__((ext_vector_type(16))) float f32x16;
typedef __attribute__((ext_vector_type(4))) int   i32x4;
typedef __attribute__((ext_vector_type(2))) unsigned u32x2;
typedef __attribute__((ext_vector_type(4))) unsigned u32x4;

#define D_MODEL 2048
#define NTOK    4096   // B*S
#define NH      16
#define HD      128
#define SEQ     2048
#define NQKV    6144   // 3*D_MODEL (concatenated q,k,v outputs)

__device__ __forceinline__ short f2bf(float f) {
  unsigned u = __builtin_bit_cast(unsigned, f);
  unsigned r = u + 0x7FFFu + ((u >> 16) & 1u);   // RNE
  return (short)(r >> 16);
}
__device__ __forceinline__ float bf2f(short s) {
  return __builtin_bit_cast(float, ((unsigned)(unsigned short)s) << 16);
}

__device__ __forceinline__ float exp2fast(float x) {
#if __has_builtin(__builtin_amdgcn_exp2f)
  return __builtin_amdgcn_exp2f(x);
#else
  return exp2f(x);
#endif
}

// pack 2 fp32 -> 2 bf16 (RNE) in one instr
__device__ __forceinline__ unsigned cvt_pk_bf16(float a, float b) {
  unsigned r;
  asm("v_cvt_pk_bf16_f32 %0, %1, %2" : "=v"(r) : "v"(a), "v"(b));
  return r;
}

// exchange: x.hi-lanes <-> y.lo-lanes. After: x = {x.lo, y.lo}, y = {x.hi, y.hi}
__device__ __forceinline__ void permswap(unsigned& x, unsigned& y) {
#if __has_builtin(__builtin_amdgcn_permlane32_swap)
  u32x2 r = __builtin_amdgcn_permlane32_swap(x, y, false, false);
  x = r[0]; y = r[1];
#else
  asm volatile("v_permlane32_swap_b32 %0, %1" : "+v"(x), "+v"(y));
#endif
}

__device__ __forceinline__ f32x16 mfma32(bf16x8 a, bf16x8 b, f32x16 c) {
  return __builtin_amdgcn_mfma_f32_32x32x16_bf16(a, b, c, 0, 0, 0);
}

// async global->LDS, 16B per lane. LDS dst must be wave-uniform; HW writes lane i at dst + i*16.
__device__ __forceinline__ void gload_lds16(const void* g, void* l) {
  typedef __attribute__((address_space(1))) const unsigned gu32;
  typedef __attribute__((address_space(3))) unsigned lu32;
  __builtin_amdgcn_global_load_lds((gu32*)(uintptr_t)g,
                                   (lu32*)(unsigned)(uintptr_t)l, 16, 0, 0);
}

// ---------------- 1. fp32 -> bf16 cast (vectorized) ----------------
__global__ __launch_bounds__(256) void cast_bf16(const float* __restrict__ in,
                                                 short* __restrict__ out, int n4) {
  int i = blockIdx.x * 256 + threadIdx.x;
  if (i >= n4) return;
  float4 v = ((const float4*)in)[i];
  short4 o;
  o.x = f2bf(v.x); o.y = f2bf(v.y); o.z = f2bf(v.z); o.w = f2bf(v.w);
  ((short4*)out)[i] = o;
}

// ---------------- 2. W (KxN) -> W^T (NxK) bf16, LDS-tiled ----------------
__global__ __launch_bounds__(256) void wtrans(const float* __restrict__ w0,
                                              const float* __restrict__ w1,
                                              const float* __restrict__ w2,
                                              const float* __restrict__ w3,
                                              short* __restrict__ wt) {
  int z = blockIdx.z;
  const float* W = (z == 0) ? w0 : (z == 1) ? w1 : (z == 2) ? w2 : w3;
  short* O = wt + (size_t)z * D_MODEL * D_MODEL;
  int n0 = blockIdx.x * 64, k0 = blockIdx.y * 64;
  __shared__ short T[64 * 136];
  int tid = threadIdx.x;
#pragma unroll
  for (int it = 0; it < 4; ++it) {
    int f = it * 256 + tid, kk = f >> 4, nc = f & 15;
    float4 v = *(const float4*)&W[(size_t)(k0 + kk) * D_MODEL + n0 + nc * 4];
    short4 o;
    o.x = f2bf(v.x); o.y = f2bf(v.y); o.z = f2bf(v.z); o.w = f2bf(v.w);
    *(short4*)&T[kk * 136 + nc * 4] = o;
  }
  __syncthreads();
#pragma unroll
  for (int it = 0; it < 4; ++it) {
    int u = it * 256 + tid, nn = u >> 4, kc = u & 15;
    short4 o;
    o.x = T[(kc * 4 + 0) * 136 + nn];
    o.y = T[(kc * 4 + 1) * 136 + nn];
    o.z = T[(kc * 4 + 2) * 136 + nn];
    o.w = T[(kc * 4 + 3) * 136 + nn];
    *(short4*)&O[(size_t)(n0 + nn) * D_MODEL + k0 + kc * 4] = o;
  }
}

// ---------------- 3/7. GEMM: 256x128 tile, BK=32, 3-deep LDS pipeline, counted vmcnt ----------------
// LDS: 3 buffers x 24KB = 72KB -> 2 blocks/CU (16 waves/CU) for cross-block barrier overlap.
// Ledger: prologue stage {0,1} -> vmcnt(3); iter jt: stage jt+2 (6 in flight) -> read jt ->
// MFMA -> vmcnt(3) [jt+1 landed, jt+2 flying] -> barrier. Tail drains vmcnt(0) once.
template <bool OUTBF16>
__global__ __launch_bounds__(512, 4) void gemm8(const short* __restrict__ A,
                                                const short* __restrict__ Bt,
                                                void* __restrict__ Cv, int CS) {
  __shared__ short L[3 * 12288];   // 73728 B
  int tid = threadIdx.x, w = tid >> 6, lane = tid & 63, c = lane & 15, g = lane >> 4;

  int gx = gridDim.x, gy = gridDim.y;
  int lin = blockIdx.x + gx * blockIdx.y;
  int idx = lin >> 3, nst = (gx * gy) >> 7;
  int s = (lin & 7) * nst + (idx >> 4);
  int w16 = idx & 15;
  int smR = gy >> 2;
  int mblk = (s % smR) * 4 + (w16 >> 2);
  int nblk = (s / smR) * 4 + (w16 & 3);
  int m0 = mblk * 256, n0 = nblk * 128;
  int wm = w >> 1, wn = w & 1;

  const int NKT = D_MODEL / 32;   // 64 K-tiles

  int asrc[2], bsrc;
#pragma unroll
  for (int q = 0; q < 2; ++q) {
    int o = (2 * w + q) * 1024 + lane * 16;
    int os = o ^ (((o >> 7) & 7) << 4);
    asrc[q] = (m0 + (os >> 6)) * D_MODEL + ((os & 63) >> 1);
  }
  {
    int o = w * 1024 + lane * 16;
    int os = o ^ (((o >> 7) & 7) << 4);
    bsrc = (n0 + (os >> 6)) * D_MODEL + ((os & 63) >> 1);
  }

  int aoff[4], boff[4];
#pragma unroll
  for (int mi = 0; mi < 4; ++mi) {
    int r = wm * 64 + mi * 16 + c;
    int o = r * 64 + g * 16;
    aoff[mi] = o ^ (((o >> 7) & 7) << 4);
  }
#pragma unroll
  for (int ni = 0; ni < 4; ++ni) {
    int r = wn * 64 + ni * 16 + c;
    int o = r * 64 + g * 16;
    boff[ni] = 16384 + (o ^ (((o >> 7) & 7) << 4));
  }

  auto STAGE = [&](int jt, int slot) {
    int kk = jt * 32;
    char* base = (char*)L + slot * 24576;
    gload_lds16(A + asrc[0] + kk, base + (2 * w) * 1024);
    gload_lds16(A + asrc[1] + kk, base + (2 * w + 1) * 1024);
    gload_lds16(Bt + bsrc + kk, base + 16384 + w * 1024);
  };

  f32x4 acc[4][4] = {};

  STAGE(0, 0); STAGE(1, 1);                        // 6 loads in flight
  asm volatile("s_waitcnt vmcnt(3)" ::: "memory"); // tile 0 landed
  __builtin_amdgcn_s_barrier();
  asm volatile("" ::: "memory");

  int rdslot = 0;
  for (int jt = 0; jt < NKT; ++jt) {
    int stslot = rdslot + 2; if (stslot >= 3) stslot -= 3;
    if (jt + 2 < NKT) STAGE(jt + 2, stslot);
    const char* buf = (const char*)L + rdslot * 24576;
    bf16x8 af[4], bfv[4];
#pragma unroll
    for (int mi = 0; mi < 4; ++mi) af[mi] = *(const bf16x8*)(buf + aoff[mi]);
#pragma unroll
    for (int ni = 0; ni < 4; ++ni) bfv[ni] = *(const bf16x8*)(buf + boff[ni]);
    __builtin_amdgcn_s_setprio(1);
#pragma unroll
    for (int mi = 0; mi < 4; ++mi)
#pragma unroll
      for (int ni = 0; ni < 4; ++ni)
        acc[mi][ni] = __builtin_amdgcn_mfma_f32_16x16x32_bf16(af[mi], bfv[ni],
                                                              acc[mi][ni], 0, 0, 0);
    __builtin_amdgcn_s_setprio(0);
    if (jt + 1 < NKT) {
      if (jt + 2 < NKT) { asm volatile("s_waitcnt vmcnt(3)" ::: "memory"); }
      else              { asm volatile("s_waitcnt vmcnt(0)" ::: "memory"); }
      __builtin_amdgcn_s_barrier();
      asm volatile("" ::: "memory");
    }
    rdslot = (rdslot == 2) ? 0 : rdslot + 1;
  }

  int row0 = m0 + wm * 64, col0 = n0 + wn * 64;
  if (OUTBF16) {
    short* Cb = (short*)Cv;
#pragma unroll
    for (int mi = 0; mi < 4; ++mi)
#pragma unroll
      for (int ni = 0; ni < 4; ++ni)
#pragma unroll
        for (int i = 0; i < 4; ++i)
          Cb[(size_t)(row0 + mi * 16 + g * 4 + i) * CS + col0 + ni * 16 + c] =
              f2bf(acc[mi][ni][i]);
  } else {
    float* Cf = (float*)Cv;
#pragma unroll
    for (int mi = 0; mi < 4; ++mi)
#pragma unroll
      for (int ni = 0; ni < 4; ++ni)
#pragma unroll
        for (int i = 0; i < 4; ++i)
          Cf[(size_t)(row0 + mi * 16 + g * 4 + i) * CS + col0 + ni * 16 + c] =
              acc[mi][ni][i];
  }
}

// ---------------- 4. fused RMSNorm + RoPE (q,k), one wave per (token,head) ----------------
__global__ __launch_bounds__(256) void norm_rope(const short* __restrict__ qkv16,
                                                 const float* __restrict__ cosb,
                                                 const float* __restrict__ sinb,
                                                 const float* __restrict__ gq,
                                                 const float* __restrict__ gk,
                                                 short* __restrict__ qn,
                                                 short* __restrict__ kn) {
  int z = blockIdx.y;  // 0=q, 1=k
  const float* gg = z ? gk : gq;
  short* O = z ? kn : qn;
  int w = threadIdx.x >> 6, lane = threadIdx.x & 63;
  int p = blockIdx.x * 4 + w;          // (token,head) pair
  int token = p >> 4, h = p & 15;
  int v = *(const int*)&qkv16[(size_t)token * NQKV + z * D_MODEL + h * HD + lane * 2];
  float x0 = bf2f((short)(v & 0xffff));
  float x1 = bf2f((short)((unsigned)v >> 16));
  float ss = x0 * x0 + x1 * x1;
#pragma unroll
  for (int mk = 32; mk; mk >>= 1) ss += __shfl_xor(ss, mk);
  float rs = rsqrtf(ss * (1.f / 128.f) + 1e-5f);
  float qs = z ? 1.0f : 0.12751744f;   // 1/sqrt(128) * log2(e) for Q only
  rs *= qs;
  float xr = x0 * rs * gg[lane * 2];
  float xi = x1 * rs * gg[lane * 2 + 1];
  float cc = cosb[(size_t)token * 64 + lane];
  float sn = sinb[(size_t)token * 64 + lane];
  float or_ = xr * cc - xi * sn;
  float oi_ = xr * sn + xi * cc;
  int b = token >> 11, sidx = token & 2047;
  size_t dst = ((size_t)(b * NH + h) * SEQ + sidx) * HD + lane * 2;
  unsigned pk = (unsigned)(unsigned short)f2bf(or_) |
                ((unsigned)(unsigned short)f2bf(oi_) << 16);
  *(unsigned*)&O[dst] = pk;
}

// ---------------- 5. V (from qkv16 [token][6144], v at +4096) -> V^T (B,H,128,S) ----------------
__global__ __launch_bounds__(256) void vtrans(const short* __restrict__ qkv16,
                                              short* __restrict__ vt) {
  int st = blockIdx.x, bh = blockIdx.y;
  int b = bh >> 4, h = bh & 15;
  int t0 = b * SEQ + st * 64;
  __shared__ short Lt[64 * 136];
  int tid = threadIdx.x;
#pragma unroll
  for (int it = 0; it < 4; ++it) {
    int f = it * 256 + tid, tk = f >> 4, ch = f & 15;
    *(i32x4*)&Lt[tk * 136 + ch * 8] =
        *(const i32x4*)&qkv16[(size_t)(t0 + tk) * NQKV + 2 * D_MODEL + h * HD + ch * 8];
  }
  __syncthreads();
#pragma unroll
  for (int it = 0; it < 4; ++it) {
    int u = it * 256 + tid, d = u >> 3, kg = u & 7;
    bf16x8 o;
#pragma unroll
    for (int j = 0; j < 8; ++j) o[j] = Lt[(kg * 8 + j) * 136 + d];
    *(bf16x8*)&vt[(size_t)(bh * HD + d) * SEQ + st * 64 + kg * 8] = o;
  }
}

// ---------------- 6. flash attention: 8 waves x 32 q-rows, 32x32x16 MFMA ----------------
// QK^T: mfma32(K, Q) -> S C-layout: col q = lane&31, row k = kt*32 + (reg&3)+8*(reg>>2)+4*hi.
// P redistributed to B-frag via cvt_pk + permlane32_swap (one swap fills words w and w+2).
// PV: mfma32(V^T, P) -> acc[db]: d = db*32 + (reg&3)+8*(reg>>2)+4*hi, q = lane&31.
// K/V LDS: XOR-swizzled (phys = row*RB + (col ^ ((row&7)<<4))), gload_lds staged, dbuf.
__global__ __launch_bounds__(512, 2) void flash(const short* __restrict__ qn,
                                                const short* __restrict__ kn,
                                                const short* __restrict__ vt,
                                                short* __restrict__ attn) {
  __shared__ short Ks[2][64 * 128];   // 2 x 16KB, [key][d]
  __shared__ short Vs[2][128 * 64];   // 2 x 16KB, [d][key]
  int tid = threadIdx.x, w = tid >> 6, lane = tid & 63;
  int q31 = lane & 31, hi = lane >> 5;

  // XCD-aware remap: XCD (phys%8) gets 4 bh x 8 q-blocks -> K/V L2-resident per XCD
  int phys = blockIdx.x;
  int xcd = phys & 7, idx = phys >> 3;
  int bh = xcd * 4 + (idx >> 3);
  int qb = idx & 7;
  int q0 = qb * 256 + w * 32;

  const size_t base = (size_t)bh * SEQ * HD;
  const short* Kg = kn + base;
  const short* Vg = vt + base;

  // Q fragments (B-side): position (hi, j) <- Q[q0+q31][d = s*16 + hi*8 + j]
  bf16x8 qf[8];
#pragma unroll
  for (int s = 0; s < 8; ++s)
    qf[s] = *(const bf16x8*)&qn[base + (size_t)(q0 + q31) * HD + s * 16 + hi * 8];

  f32x16 acc[4] = {};
  float m_ = -1e30f, l_ = 0.f;

  // staging source offsets (same swizzle as reads)
  int ksrc[2], vsrc[2];
#pragma unroll
  for (int p = 0; p < 2; ++p) {
    int ch = w * 2 + p;
    int o = ch * 1024 + lane * 16;
    int kr = o >> 8, kc = o & 255;                   // K: 256B rows
    ksrc[p] = kr * HD + ((kc ^ ((kr & 7) << 4)) >> 1);
    int vr = o >> 7, vc = o & 127;                   // V: 128B rows
    vsrc[p] = vr * SEQ + ((vc ^ ((vr & 7) << 4)) >> 1);
  }
  // read offsets (bytes), loop-invariant; row&7 == q31&7 for all rows used
  int swz = (q31 & 7) << 4;
  int koff[8], voff[4];
#pragma unroll
  for (int kf = 0; kf < 8; ++kf) koff[kf] = (kf * 32 + hi * 16) ^ swz;
#pragma unroll
  for (int kk = 0; kk < 4; ++kk) voff[kk] = (kk * 32 + hi * 16) ^ swz;
  int krow0 = q31 * 256, krow1 = (32 + q31) * 256;

  // prologue: stage tile 0 into buffer 0
#pragma unroll
  for (int p = 0; p < 2; ++p) {
    int ch = w * 2 + p;
    gload_lds16(Kg + ksrc[p], (char*)&Ks[0][0] + ch * 1024);
    gload_lds16(Vg + vsrc[p], (char*)&Vs[0][0] + ch * 1024);
  }

  const int NT = SEQ / 64;
  for (int t = 0; t < NT; ++t) {
    int cur = t & 1;
    __syncthreads();           // vmcnt(0) drain => buf[cur] ready; buf[cur^1] free
    if (t + 1 < NT) {
      int k0n = (t + 1) * 64;
#pragma unroll
      for (int p = 0; p < 2; ++p) {
        int ch = w * 2 + p;
        gload_lds16(Kg + (size_t)k0n * HD + ksrc[p], (char*)&Ks[cur ^ 1][0] + ch * 1024);
        gload_lds16(Vg + k0n + vsrc[p],              (char*)&Vs[cur ^ 1][0] + ch * 1024);
      }
    }
    const char* Kb = (const char*)&Ks[cur][0];
    const char* Vb = (const char*)&Vs[cur][0];

    // QK^T: two 32x32 blocks (keys 0-31, 32-63), K=128 over 8 slices
    f32x16 s0 = {0,0,0,0,0,0,0,0,0,0,0,0,0,0,0,0};
    f32x16 s1 = {0,0,0,0,0,0,0,0,0,0,0,0,0,0,0,0};
    __builtin_amdgcn_s_setprio(1);
#pragma unroll
    for (int kf = 0; kf < 8; ++kf) {
      bf16x8 k0 = *(const bf16x8*)(Kb + krow0 + koff[kf]);
      s0 = mfma32(k0, qf[kf], s0);
      bf16x8 k1 = *(const bf16x8*)(Kb + krow1 + koff[kf]);
      s1 = mfma32(k1, qf[kf], s1);
    }
    __builtin_amdgcn_s_setprio(0);

    // per-lane scalar online softmax (q = q31); halves hold disjoint k's of same q
    float p0 = -1e30f, p1 = -1e30f, p2 = -1e30f, p3 = -1e30f;
#pragma unroll
    for (int i = 0; i < 4; ++i) {
      p0 = fmaxf(p0, fmaxf(s0[i], s0[i + 4]));
      p1 = fmaxf(p1, fmaxf(s0[i + 8], s0[i + 12]));
      p2 = fmaxf(p2, fmaxf(s1[i], s1[i + 4]));
      p3 = fmaxf(p3, fmaxf(s1[i + 8], s1[i + 12]));
    }
    float pmax = fmaxf(fmaxf(p0, p1), fmaxf(p2, p3));
    pmax = fmaxf(pmax, __shfl_xor(pmax, 32));
    if (!__all(pmax <= m_ + 11.5f)) {   // defer-max: p bounded by 2^11.5
      float mn = fmaxf(m_, pmax);
      float al = exp2fast(m_ - mn);
      m_ = mn; l_ *= al;
#pragma unroll
      for (int db = 0; db < 4; ++db)
#pragma unroll
        for (int i = 0; i < 16; ++i) acc[db][i] *= al;
    }
    float r0 = 0.f, r1 = 0.f;
#pragma unroll
    for (int i = 0; i < 16; ++i) {
      float pa = exp2fast(s0[i] - m_); r0 += pa; s0[i] = pa;
      float pb = exp2fast(s1[i] - m_); r1 += pb; s1[i] = pb;
    }
    float r = r0 + r1;
    r += __shfl_xor(r, 32);
    l_ += r;

    // pack P -> B-frags and PV. For chunk kk = kt*2+c2:
    //   x0=pk(s[c2*8+0],s[c2*8+1]) x1=pk(s[c2*8+2],s[c2*8+3])  (q4 = c2*2)
    //   y0=pk(s[c2*8+4],s[c2*8+5]) y1=pk(s[c2*8+6],s[c2*8+7])  (q4 = c2*2+1)
    //   permswap(x0,y0): x0 -> frag reg0 (j0,1), y0 -> reg2 (j4,5); likewise x1/y1 -> reg1/reg3
    __builtin_amdgcn_s_setprio(1);
#pragma unroll
    for (int kt = 0; kt < 2; ++kt) {
      const f32x16& sv = kt ? s1 : s0;
#pragma unroll
      for (int c2 = 0; c2 < 2; ++c2) {
        unsigned x0 = cvt_pk_bf16(sv[c2 * 8 + 0], sv[c2 * 8 + 1]);
        unsigned x1 = cvt_pk_bf16(sv[c2 * 8 + 2], sv[c2 * 8 + 3]);
        unsigned y0 = cvt_pk_bf16(sv[c2 * 8 + 4], sv[c2 * 8 + 5]);
        unsigned y1 = cvt_pk_bf16(sv[c2 * 8 + 6], sv[c2 * 8 + 7]);
        permswap(x0, y0);
        permswap(x1, y1);
        u32x4 pw = {x0, x1, y0, y1};
        bf16x8 pfrag = __builtin_bit_cast(bf16x8, pw);
        int vo = voff[kt * 2 + c2];
#pragma unroll
        for (int db = 0; db < 4; ++db) {
          bf16x8 va = *(const bf16x8*)(Vb + (db * 32 + q31) * 128 + vo);
          acc[db] = mfma32(va, pfrag, acc[db]);
        }
      }
    }
    __builtin_amdgcn_s_setprio(0);
  }

  int b = bh >> 4, h = bh & 15;
  float linv = 1.f / l_;
  size_t orow = (size_t)(b * SEQ + q0 + q31) * D_MODEL + h * HD;
#pragma unroll
  for (int db = 0; db < 4; ++db)
#pragma unroll
    for (int rg = 0; rg < 4; ++rg) {
      short4 o;
      o.x = f2bf(acc[db][rg * 4 + 0] * linv);
      o.y = f2bf(acc[db][rg * 4 + 1] * linv);
      o.z = f2bf(acc[db][rg * 4 + 2] * linv);
      o.w = f2bf(acc[db][rg * 4 + 3] * linv);
      *(short4*)&attn[orow + db * 32 + rg * 8 + hi * 4] = o;
    }
}

// ---------------- launch ----------------
extern "C" void kernel_launch(void* const* d_in, const int* in_sizes, int n_in,
                              void* d_out, int out_size, void* d_ws, size_t ws_size,
                              hipStream_t stream) {
  const float* hs   = (const float*)d_in[0];
  const float* fcos = (const float*)d_in[1];
  const float* fsin = (const float*)d_in[2];
  const float* Wq   = (const float*)d_in[3];
  const float* Wk   = (const float*)d_in[4];
  const float* Wv   = (const float*)d_in[5];
  const float* Wo   = (const float*)d_in[6];
  const float* gq   = (const float*)d_in[7];
  const float* gk   = (const float*)d_in[8];

  char* ws = (char*)d_ws;
  short* hs16  = (short*)ws;                        // 16,777,216 B (reused as attn16 later)
  short* Wt    = (short*)(ws + 16777216);           // 33,554,432 B ([Wq|Wk|Wv|Wo] N-major)
  short* qkv16 = (short*)(ws + 50331648);           // 50,331,648 B ([token][6144])
  short* qn    = (short*)(ws + 100663296);          // 16,777,216 B (B,H,S,128)
  short* kn    = (short*)(ws + 117440512);          // 16,777,216 B
  short* vt    = (short*)(ws + 134217728);          // 16,777,216 B (B,H,128,S)
  short* attn16 = hs16;  // hs16 dead after QKV GEMM

  cast_bf16<<<8192, 256, 0, stream>>>(hs, hs16, NTOK * D_MODEL / 4);
  wtrans<<<dim3(32, 32, 4), 256, 0, stream>>>(Wq, Wk, Wv, Wo, Wt);
  // QKV: M=4096 x N=6144, grid 48x16 = 768 blocks (3 per CU over the run)
  gemm8<true><<<dim3(48, 16), 512, 0, stream>>>(hs16, Wt, qkv16, NQKV);
  norm_rope<<<dim3(16384, 2), 256, 0, stream>>>(qkv16, fcos, fsin, gq, gk, qn, kn);
  vtrans<<<dim3(32, 32), 256, 0, stream>>>(qkv16, vt);
  flash<<<dim3(256), 512, 0, stream>>>(qn, kn, vt, attn16);
  // Wo: M=4096 x N=2048, grid 16x16 = 256 blocks
  gemm8<false><<<dim3(16, 16), 512, 0, stream>>>(attn16,
                                                 Wt + (size_t)3 * D_MODEL * D_MODEL,
                                                 d_out, D_MODEL);
}